// Round 2
// baseline (10199.593 us; speedup 1.0000x reference)
//
#include <hip/hip_runtime.h>
#include <hip/hip_bf16.h>

typedef __hip_bfloat16 bf16;

constexpr int nB = 2;
constexpr int nS = 2048;
constexpr int nHID = 2048;
constexpr int nH = 16;
constexpr int nKV = 8;
constexpr int nD = 128;
constexpr float kEps = 1e-6f;
constexpr float kScale = 0.08838834764831845f;  // 1/sqrt(128)

__device__ inline float b2f(unsigned short u) {
  return __uint_as_float(((unsigned)u) << 16);
}
__device__ inline float bf2f(bf16 v) { return __bfloat162float(v); }

// ---------------------------------------------------------------------------
// Projection GEMM: C[M,N](bf16) = A[M,K](f32) @ B[K,N](f32), fp32 accumulate.
// 64x64 tile, BK=16, 256 threads, 4x4 microtile.
// ---------------------------------------------------------------------------
__global__ __launch_bounds__(256) void gemm_proj(
    const float* __restrict__ A, const float* __restrict__ Bm,
    bf16* __restrict__ C, int M, int N, int K) {
  __shared__ float As[16][68];  // As[k][m], padded
  __shared__ float Bs[16][68];  // Bs[k][n], padded
  const int tid = threadIdx.x;
  const int tx = tid & 15, ty = tid >> 4;
  const int m0 = blockIdx.y * 64, n0 = blockIdx.x * 64;
  const int ar = tid >> 2, ac = (tid & 3) * 4;   // A: row ar, 4 k's at ac
  const int br = tid >> 4, bc = (tid & 15) * 4;  // B: k br, 4 n's at bc
  float acc[4][4] = {};
  for (int k0 = 0; k0 < K; k0 += 16) {
    const float4 va =
        *reinterpret_cast<const float4*>(A + (size_t)(m0 + ar) * K + k0 + ac);
    const float4 vb =
        *reinterpret_cast<const float4*>(Bm + (size_t)(k0 + br) * N + n0 + bc);
    As[ac + 0][ar] = va.x;
    As[ac + 1][ar] = va.y;
    As[ac + 2][ar] = va.z;
    As[ac + 3][ar] = va.w;
    Bs[br][bc + 0] = vb.x;
    Bs[br][bc + 1] = vb.y;
    Bs[br][bc + 2] = vb.z;
    Bs[br][bc + 3] = vb.w;
    __syncthreads();
#pragma unroll
    for (int kk = 0; kk < 16; ++kk) {
      const float4 a = *reinterpret_cast<const float4*>(&As[kk][ty * 4]);
      const float4 b = *reinterpret_cast<const float4*>(&Bs[kk][tx * 4]);
      const float av[4] = {a.x, a.y, a.z, a.w};
      const float bv[4] = {b.x, b.y, b.z, b.w};
#pragma unroll
      for (int i = 0; i < 4; ++i)
#pragma unroll
        for (int j = 0; j < 4; ++j) acc[i][j] += av[i] * bv[j];
    }
    __syncthreads();
  }
#pragma unroll
  for (int i = 0; i < 4; ++i) {
    const size_t row = (size_t)(m0 + ty * 4 + i) * N + n0 + tx * 4;
#pragma unroll
    for (int j = 0; j < 4; ++j) C[row + j] = __float2bfloat16(acc[i][j]);
  }
}

// ---------------------------------------------------------------------------
// Output GEMM: C[M,N](f32) = A[M,K](bf16) @ B[K,N](f32), fp32 accumulate.
// ---------------------------------------------------------------------------
__global__ __launch_bounds__(256) void gemm_out(
    const bf16* __restrict__ A, const float* __restrict__ Bm,
    float* __restrict__ C, int M, int N, int K) {
  __shared__ float As[16][68];
  __shared__ float Bs[16][68];
  const int tid = threadIdx.x;
  const int tx = tid & 15, ty = tid >> 4;
  const int m0 = blockIdx.y * 64, n0 = blockIdx.x * 64;
  const int ar = tid >> 2, ac = (tid & 3) * 4;
  const int br = tid >> 4, bc = (tid & 15) * 4;
  float acc[4][4] = {};
  for (int k0 = 0; k0 < K; k0 += 16) {
    const ushort4 va =
        *reinterpret_cast<const ushort4*>(A + (size_t)(m0 + ar) * K + k0 + ac);
    const float4 vb =
        *reinterpret_cast<const float4*>(Bm + (size_t)(k0 + br) * N + n0 + bc);
    As[ac + 0][ar] = b2f(va.x);
    As[ac + 1][ar] = b2f(va.y);
    As[ac + 2][ar] = b2f(va.z);
    As[ac + 3][ar] = b2f(va.w);
    Bs[br][bc + 0] = vb.x;
    Bs[br][bc + 1] = vb.y;
    Bs[br][bc + 2] = vb.z;
    Bs[br][bc + 3] = vb.w;
    __syncthreads();
#pragma unroll
    for (int kk = 0; kk < 16; ++kk) {
      const float4 a = *reinterpret_cast<const float4*>(&As[kk][ty * 4]);
      const float4 b = *reinterpret_cast<const float4*>(&Bs[kk][tx * 4]);
      const float av[4] = {a.x, a.y, a.z, a.w};
      const float bv[4] = {b.x, b.y, b.z, b.w};
#pragma unroll
      for (int i = 0; i < 4; ++i)
#pragma unroll
        for (int j = 0; j < 4; ++j) acc[i][j] += av[i] * bv[j];
    }
    __syncthreads();
  }
#pragma unroll
  for (int i = 0; i < 4; ++i) {
    const size_t row = (size_t)(m0 + ty * 4 + i) * N + n0 + tx * 4;
#pragma unroll
    for (int j = 0; j < 4; ++j) C[row + j] = acc[i][j];
  }
}

// ---------------------------------------------------------------------------
// Per-head RMSNorm + RoPE, in place on bf16. One 128-thread block per
// (token, head). positions == arange(S) so row index gives the position.
// ---------------------------------------------------------------------------
__global__ __launch_bounds__(128) void norm_rope_kernel(
    bf16* __restrict__ x, const float* __restrict__ w, int NHd) {
  const int row = blockIdx.x;  // b*S + s
  const int head = blockIdx.y;
  const int t = threadIdx.x;  // 0..127 = head dim
  const int s = row & (nS - 1);
  bf16* xp = x + ((size_t)row * NHd + head) * nD;
  const float v = bf2f(xp[t]);
  float ss = v * v;
#pragma unroll
  for (int off = 32; off > 0; off >>= 1) ss += __shfl_xor(ss, off);
  __shared__ float wsum[2];
  __shared__ float buf[nD];
  if ((t & 63) == 0) wsum[t >> 6] = ss;
  __syncthreads();
  const float inv = rsqrtf((wsum[0] + wsum[1]) * (1.0f / nD) + kEps);
  const float nv = v * inv * w[t];
  buf[t] = nv;
  __syncthreads();
  const float partner = buf[t ^ 64];
  const float rot = (t < 64) ? -partner : partner;
  const int j = t & 63;
  // inv_freq[j] = theta^(-j/64) = exp(-j/64 * ln(1e6))
  const float invf = expf(-(float)j * (13.815510557964274f / 64.0f));
  const float ang = (float)s * invf;
  const float outv = nv * cosf(ang) + rot * sinf(ang);
  xp[t] = __float2bfloat16(outv);
}

// ---------------------------------------------------------------------------
// Causal GQA flash attention on bf16 intermediates. One 128-thread block per
// (b, h, q_row). 64-key tiles in LDS, online softmax.
// ---------------------------------------------------------------------------
constexpr int TN = 64;
__global__ __launch_bounds__(128) void attn_kernel(
    const bf16* __restrict__ Q, const bf16* __restrict__ Kg,
    const bf16* __restrict__ Vg, bf16* __restrict__ O) {
  const int qi = blockIdx.x;
  const int bh = blockIdx.y;
  const int b = bh >> 4, h = bh & 15;
  const int kvh = h >> 1;  // h / (H/KV)
  const int t = threadIdx.x;

  __shared__ bf16 Ks[TN][nD + 2];
  __shared__ bf16 Vs[TN][nD + 2];
  __shared__ float qs[nD];
  __shared__ float part[128];
  __shared__ float sc_s[TN];
  __shared__ float pbuf[TN];

  qs[t] = bf2f(Q[((size_t)(b * nS + qi) * nH + h) * nD + t]);

  const bf16* Kbase = Kg + ((size_t)b * nS * nKV + kvh) * nD;
  const bf16* Vbase = Vg + ((size_t)b * nS * nKV + kvh) * nD;

  float m = -1e30f, l = 0.0f, acc = 0.0f;

  for (int tile = 0; tile <= qi; tile += TN) {
    const int nk = min(TN, qi - tile + 1);
    __syncthreads();  // previous tile fully consumed (and qs visible, 1st it)
#pragma unroll 4
    for (int i = 0; i < TN; ++i) {
      const size_t off = (size_t)(tile + i) * (nKV * nD) + t;
      Ks[i][t] = Kbase[off];
      Vs[i][t] = Vbase[off];
    }
    __syncthreads();
    {
      const int j = t & 63;
      const int d0 = (t >> 6) * 64;
      float sdot = 0.0f;
#pragma unroll 8
      for (int d = d0; d < d0 + 64; ++d) sdot += qs[d] * bf2f(Ks[j][d]);
      part[t] = sdot;
    }
    __syncthreads();
    if (t < TN) sc_s[t] = (t < nk) ? (part[t] + part[t + 64]) * kScale : -1e30f;
    __syncthreads();
    float mt = m;
#pragma unroll 8
    for (int jj = 0; jj < TN; ++jj) mt = fmaxf(mt, sc_s[jj]);
    const float corr = expf(m - mt);
    if (t < TN) pbuf[t] = expf(sc_s[t] - mt);
    __syncthreads();
    float ls = 0.0f, av = 0.0f;
#pragma unroll 8
    for (int jj = 0; jj < TN; ++jj) {
      const float p = pbuf[jj];
      ls += p;
      av = fmaf(p, bf2f(Vs[jj][t]), av);
    }
    l = l * corr + ls;
    acc = acc * corr + av;
    m = mt;
  }
  O[((size_t)(b * nS + qi) * nH + h) * nD + t] = __float2bfloat16(acc / l);
}

// ---------------------------------------------------------------------------
extern "C" void kernel_launch(void* const* d_in, const int* in_sizes, int n_in,
                              void* d_out, int out_size, void* d_ws,
                              size_t ws_size, hipStream_t stream) {
  const float* hs = (const float*)d_in[0];  // (B*S, HID)
  const float* Wq = (const float*)d_in[1];  // (HID, H*D)
  const float* Wk = (const float*)d_in[2];  // (HID, KV*D)
  const float* Wv = (const float*)d_in[3];  // (HID, KV*D)
  const float* Wo = (const float*)d_in[4];  // (H*D, HID)
  const float* qw = (const float*)d_in[5];  // (D,)
  const float* kw = (const float*)d_in[6];  // (D,)
  // d_in[7] positions == arange(S) (unused), d_in[8] mask == triu (unused)

  char* ws = (char*)d_ws;
  bf16* q = (bf16*)ws;                                    // B*S*H*D
  bf16* k = (bf16*)(ws + (size_t)nB * nS * nH * nD * 2);  // B*S*KV*D
  bf16* v = k + (size_t)nB * nS * nKV * nD;
  bf16* att = v + (size_t)nB * nS * nKV * nD;  // B*S*H*D
  float* out = (float*)d_out;

  const int M = nB * nS;
  gemm_proj<<<dim3(nH * nD / 64, M / 64), 256, 0, stream>>>(hs, Wq, q, M, nH * nD, nHID);
  gemm_proj<<<dim3(nKV * nD / 64, M / 64), 256, 0, stream>>>(hs, Wk, k, M, nKV * nD, nHID);
  gemm_proj<<<dim3(nKV * nD / 64, M / 64), 256, 0, stream>>>(hs, Wv, v, M, nKV * nD, nHID);
  norm_rope_kernel<<<dim3(M, nH), 128, 0, stream>>>(q, qw, nH);
  norm_rope_kernel<<<dim3(M, nKV), 128, 0, stream>>>(k, kw, nKV);
  attn_kernel<<<dim3(nS, nB * nH), 128, 0, stream>>>(q, k, v, att);
  gemm_out<<<dim3(nHID / 64, M / 64), 256, 0, stream>>>(att, Wo, out, M, nHID, nH * nD);
}

// Round 3
// 1592.035 us; speedup vs baseline: 6.4066x; 6.4066x over previous
//
#include <hip/hip_runtime.h>
#include <hip/hip_bf16.h>

typedef __hip_bfloat16 bf16;
typedef __attribute__((ext_vector_type(8))) short short8v;
typedef __attribute__((ext_vector_type(4))) float f32x4;

constexpr int nB = 2;
constexpr int nS = 2048;
constexpr int nHID = 2048;
constexpr int nH = 16;
constexpr int nKV = 8;
constexpr int nD = 128;
constexpr float kEps = 1e-6f;
constexpr float kScale = 0.08838834764831845f;  // 1/sqrt(128)

__device__ inline float b2f(unsigned short u) {
  return __uint_as_float(((unsigned)u) << 16);
}
__device__ inline float bf2f(bf16 v) { return __bfloat162float(v); }
__device__ inline short f2bs(float f) {
  bf16 h = __float2bfloat16(f);
  return *reinterpret_cast<short*>(&h);
}

// ---------------------------------------------------------------------------
// Projection GEMM: C[M,N](bf16) = A[M,K](f32) @ B[K,N](f32), fp32 accumulate.
// ---------------------------------------------------------------------------
__global__ __launch_bounds__(256) void gemm_proj(
    const float* __restrict__ A, const float* __restrict__ Bm,
    bf16* __restrict__ C, int M, int N, int K) {
  __shared__ float As[16][68];
  __shared__ float Bs[16][68];
  const int tid = threadIdx.x;
  const int tx = tid & 15, ty = tid >> 4;
  const int m0 = blockIdx.y * 64, n0 = blockIdx.x * 64;
  const int ar = tid >> 2, ac = (tid & 3) * 4;
  const int br = tid >> 4, bc = (tid & 15) * 4;
  float acc[4][4] = {};
  for (int k0 = 0; k0 < K; k0 += 16) {
    const float4 va =
        *reinterpret_cast<const float4*>(A + (size_t)(m0 + ar) * K + k0 + ac);
    const float4 vb =
        *reinterpret_cast<const float4*>(Bm + (size_t)(k0 + br) * N + n0 + bc);
    As[ac + 0][ar] = va.x;
    As[ac + 1][ar] = va.y;
    As[ac + 2][ar] = va.z;
    As[ac + 3][ar] = va.w;
    Bs[br][bc + 0] = vb.x;
    Bs[br][bc + 1] = vb.y;
    Bs[br][bc + 2] = vb.z;
    Bs[br][bc + 3] = vb.w;
    __syncthreads();
#pragma unroll
    for (int kk = 0; kk < 16; ++kk) {
      const float4 a = *reinterpret_cast<const float4*>(&As[kk][ty * 4]);
      const float4 b = *reinterpret_cast<const float4*>(&Bs[kk][tx * 4]);
      const float av[4] = {a.x, a.y, a.z, a.w};
      const float bv[4] = {b.x, b.y, b.z, b.w};
#pragma unroll
      for (int i = 0; i < 4; ++i)
#pragma unroll
        for (int j = 0; j < 4; ++j) acc[i][j] += av[i] * bv[j];
    }
    __syncthreads();
  }
#pragma unroll
  for (int i = 0; i < 4; ++i) {
    const size_t row = (size_t)(m0 + ty * 4 + i) * N + n0 + tx * 4;
#pragma unroll
    for (int j = 0; j < 4; ++j) C[row + j] = __float2bfloat16(acc[i][j]);
  }
}

// ---------------------------------------------------------------------------
// Output GEMM: C[M,N](f32) = A[M,K](bf16) @ B[K,N](f32), fp32 accumulate.
// ---------------------------------------------------------------------------
__global__ __launch_bounds__(256) void gemm_out(
    const bf16* __restrict__ A, const float* __restrict__ Bm,
    float* __restrict__ C, int M, int N, int K) {
  __shared__ float As[16][68];
  __shared__ float Bs[16][68];
  const int tid = threadIdx.x;
  const int tx = tid & 15, ty = tid >> 4;
  const int m0 = blockIdx.y * 64, n0 = blockIdx.x * 64;
  const int ar = tid >> 2, ac = (tid & 3) * 4;
  const int br = tid >> 4, bc = (tid & 15) * 4;
  float acc[4][4] = {};
  for (int k0 = 0; k0 < K; k0 += 16) {
    const ushort4 va =
        *reinterpret_cast<const ushort4*>(A + (size_t)(m0 + ar) * K + k0 + ac);
    const float4 vb =
        *reinterpret_cast<const float4*>(Bm + (size_t)(k0 + br) * N + n0 + bc);
    As[ac + 0][ar] = b2f(va.x);
    As[ac + 1][ar] = b2f(va.y);
    As[ac + 2][ar] = b2f(va.z);
    As[ac + 3][ar] = b2f(va.w);
    Bs[br][bc + 0] = vb.x;
    Bs[br][bc + 1] = vb.y;
    Bs[br][bc + 2] = vb.z;
    Bs[br][bc + 3] = vb.w;
    __syncthreads();
#pragma unroll
    for (int kk = 0; kk < 16; ++kk) {
      const float4 a = *reinterpret_cast<const float4*>(&As[kk][ty * 4]);
      const float4 b = *reinterpret_cast<const float4*>(&Bs[kk][tx * 4]);
      const float av[4] = {a.x, a.y, a.z, a.w};
      const float bv[4] = {b.x, b.y, b.z, b.w};
#pragma unroll
      for (int i = 0; i < 4; ++i)
#pragma unroll
        for (int j = 0; j < 4; ++j) acc[i][j] += av[i] * bv[j];
    }
    __syncthreads();
  }
#pragma unroll
  for (int i = 0; i < 4; ++i) {
    const size_t row = (size_t)(m0 + ty * 4 + i) * N + n0 + tx * 4;
#pragma unroll
    for (int j = 0; j < 4; ++j) C[row + j] = acc[i][j];
  }
}

// ---------------------------------------------------------------------------
// Per-head RMSNorm + RoPE, in place on bf16.
// ---------------------------------------------------------------------------
__global__ __launch_bounds__(128) void norm_rope_kernel(
    bf16* __restrict__ x, const float* __restrict__ w, int NHd) {
  const int row = blockIdx.x;  // b*S + s
  const int head = blockIdx.y;
  const int t = threadIdx.x;  // 0..127 = head dim
  const int s = row & (nS - 1);
  bf16* xp = x + ((size_t)row * NHd + head) * nD;
  const float v = bf2f(xp[t]);
  float ss = v * v;
#pragma unroll
  for (int off = 32; off > 0; off >>= 1) ss += __shfl_xor(ss, off);
  __shared__ float wsum[2];
  __shared__ float buf[nD];
  if ((t & 63) == 0) wsum[t >> 6] = ss;
  __syncthreads();
  const float inv = rsqrtf((wsum[0] + wsum[1]) * (1.0f / nD) + kEps);
  const float nv = v * inv * w[t];
  buf[t] = nv;
  __syncthreads();
  const float partner = buf[t ^ 64];
  const float rot = (t < 64) ? -partner : partner;
  const int j = t & 63;
  const float invf = expf(-(float)j * (13.815510557964274f / 64.0f));
  const float ang = (float)s * invf;
  const float outv = nv * cosf(ang) + rot * sinf(ang);
  xp[t] = __float2bfloat16(outv);
}

// ---------------------------------------------------------------------------
// MFMA causal GQA flash attention.
// Block = 256 threads = 4 waves; block owns 64 q-rows of one (b,h);
// wave w owns q-rows [q0+16w, q0+16w+16). K/V tiles of 64 keys.
//
// mfma_f32_16x16x32_bf16 layouts (learn_hip m89-verified):
//   A[r][k]: lane&15 = r, k = 8*(lane>>4)+j   (j=0..7, contiguous)
//   B[k][c]: lane&15 = c, k = 8*(lane>>4)+j
//   D[r][c]: lane&15 = c, r = 4*(lane>>4)+reg
//
// QK^T: A = Q-rows (regs), B = K from LDS row-major (row=key).
// PV:   A = P via wave-private LDS relayout, B = V transposed in LDS.
// ---------------------------------------------------------------------------
constexpr int BQ = 64, BKT = 64;

__global__ __launch_bounds__(256) void attn_mfma(
    const bf16* __restrict__ Q, const bf16* __restrict__ Kg,
    const bf16* __restrict__ Vg, bf16* __restrict__ O) {
  const int qb = (int)gridDim.x - 1 - (int)blockIdx.x;  // heavy blocks first
  const int q0 = qb * BQ;
  const int bh = blockIdx.y;
  const int b = bh >> 4, h = bh & 15, kvh = h >> 1;
  const int tid = threadIdx.x;
  const int wave = tid >> 6, lane = tid & 63;
  const int lr = lane & 15, lg = lane >> 4;

  __shared__ bf16 Ks[BKT][136];      // +8 pad: row stride 272B (2-way max)
  __shared__ bf16 Vt[nD][72];        // transposed V; stride 144B
  __shared__ bf16 Pl[4][16][72];     // wave-private P relayout buffer

  // Q A-fragments, held in registers for the whole kernel
  short8v qf[4];
  {
    const bf16* qrow =
        Q + ((size_t)(b * nS + q0 + 16 * wave + lr) * nH + h) * nD;
#pragma unroll
    for (int dc = 0; dc < 4; ++dc)
      qf[dc] = *reinterpret_cast<const short8v*>(qrow + 32 * dc + 8 * lg);
  }

  const bf16* Kbase = Kg + (size_t)b * nS * (nKV * nD) + (size_t)kvh * nD;
  const bf16* Vbase = Vg + (size_t)b * nS * (nKV * nD) + (size_t)kvh * nD;

  f32x4 of[8];
#pragma unroll
  for (int n = 0; n < 8; ++n) of[n] = (f32x4){0.f, 0.f, 0.f, 0.f};
  float mrow[4] = {-1e30f, -1e30f, -1e30f, -1e30f};
  float lrow[4] = {0.f, 0.f, 0.f, 0.f};

  const int krow = tid >> 2, kcc = (tid & 3) * 32;   // K staging coords
  const int vkey = tid & 63, vdc = (tid >> 6) * 32;  // V staging coords

  for (int kt0 = 0; kt0 <= q0; kt0 += BKT) {
    __syncthreads();  // previous tile fully consumed
    // ---- stage K row-major
    {
      const bf16* src = Kbase + (size_t)(kt0 + krow) * (nKV * nD) + kcc;
#pragma unroll
      for (int i = 0; i < 4; ++i)
        *reinterpret_cast<short8v*>(&Ks[krow][kcc + 8 * i]) =
            *reinterpret_cast<const short8v*>(src + 8 * i);
    }
    // ---- stage V transposed (scalar writes, 2B stride across lanes)
    {
      const bf16* src = Vbase + (size_t)(kt0 + vkey) * (nKV * nD) + vdc;
#pragma unroll
      for (int i = 0; i < 4; ++i) {
        const short8v v = *reinterpret_cast<const short8v*>(src + 8 * i);
#pragma unroll
        for (int j = 0; j < 8; ++j)
          *reinterpret_cast<short*>(&Vt[vdc + 8 * i + j][vkey]) = v[j];
      }
    }
    __syncthreads();

    // ---- QK^T: S[16 rows][64 keys] per wave, 4 col-subtiles
    f32x4 sfr[4];
#pragma unroll
    for (int sub = 0; sub < 4; ++sub) {
      f32x4 acc = {0.f, 0.f, 0.f, 0.f};
#pragma unroll
      for (int dc = 0; dc < 4; ++dc) {
        const short8v kf = *reinterpret_cast<const short8v*>(
            &Ks[16 * sub + lr][32 * dc + 8 * lg]);
        acc = __builtin_amdgcn_mfma_f32_16x16x32_bf16(qf[dc], kf, acc, 0, 0, 0);
      }
      sfr[sub] = acc;
    }

    // ---- scale + causal mask (only the diagonal tile needs it)
    const bool diag = (kt0 == q0);
#pragma unroll
    for (int sub = 0; sub < 4; ++sub)
#pragma unroll
      for (int r = 0; r < 4; ++r) {
        float s = sfr[sub][r] * kScale;
        if (diag && (16 * sub + lr > 16 * wave + 4 * lg + r)) s = -1e30f;
        sfr[sub][r] = s;
      }

    // ---- online softmax: per-lane rows r=0..3, stats across lane&15 group
    float mt[4];
#pragma unroll
    for (int r = 0; r < 4; ++r) {
      float v = fmaxf(fmaxf(sfr[0][r], sfr[1][r]), fmaxf(sfr[2][r], sfr[3][r]));
#pragma unroll
      for (int off = 1; off < 16; off <<= 1) v = fmaxf(v, __shfl_xor(v, off));
      mt[r] = fmaxf(mrow[r], v);
    }
#pragma unroll
    for (int sub = 0; sub < 4; ++sub)
#pragma unroll
      for (int r = 0; r < 4; ++r) sfr[sub][r] = __expf(sfr[sub][r] - mt[r]);
#pragma unroll
    for (int r = 0; r < 4; ++r) {
      float ps = sfr[0][r] + sfr[1][r] + sfr[2][r] + sfr[3][r];
#pragma unroll
      for (int off = 1; off < 16; off <<= 1) ps += __shfl_xor(ps, off);
      const float corr = __expf(mrow[r] - mt[r]);
      lrow[r] = lrow[r] * corr + ps;
      mrow[r] = mt[r];
#pragma unroll
      for (int n = 0; n < 8; ++n) of[n][r] *= corr;
    }

    // ---- P -> wave-private LDS (bf16), relayout D-frag -> A-frag
#pragma unroll
    for (int sub = 0; sub < 4; ++sub)
#pragma unroll
      for (int r = 0; r < 4; ++r)
        *reinterpret_cast<short*>(&Pl[wave][4 * lg + r][16 * sub + lr]) =
            f2bs(sfr[sub][r]);

    // ---- PV: O[16][128] += P[16][64] @ V[64][128]
    short8v pa[2];
#pragma unroll
    for (int c = 0; c < 2; ++c)
      pa[c] =
          *reinterpret_cast<const short8v*>(&Pl[wave][lr][32 * c + 8 * lg]);
#pragma unroll
    for (int n = 0; n < 8; ++n)
#pragma unroll
      for (int c = 0; c < 2; ++c) {
        const short8v vf = *reinterpret_cast<const short8v*>(
            &Vt[16 * n + lr][32 * c + 8 * lg]);
        of[n] = __builtin_amdgcn_mfma_f32_16x16x32_bf16(pa[c], vf, of[n], 0, 0, 0);
      }
  }

  // ---- epilogue: normalize and store
#pragma unroll
  for (int r = 0; r < 4; ++r) {
    const float inv = 1.0f / lrow[r];
    bf16* orow =
        O + ((size_t)(b * nS + q0 + 16 * wave + 4 * lg + r) * nH + h) * nD;
#pragma unroll
    for (int n = 0; n < 8; ++n)
      orow[16 * n + lr] = __float2bfloat16(of[n][r] * inv);
  }
}

// ---------------------------------------------------------------------------
extern "C" void kernel_launch(void* const* d_in, const int* in_sizes, int n_in,
                              void* d_out, int out_size, void* d_ws,
                              size_t ws_size, hipStream_t stream) {
  const float* hs = (const float*)d_in[0];
  const float* Wq = (const float*)d_in[1];
  const float* Wk = (const float*)d_in[2];
  const float* Wv = (const float*)d_in[3];
  const float* Wo = (const float*)d_in[4];
  const float* qw = (const float*)d_in[5];
  const float* kw = (const float*)d_in[6];

  char* ws = (char*)d_ws;
  bf16* q = (bf16*)ws;                                    // B*S*H*D
  bf16* k = (bf16*)(ws + (size_t)nB * nS * nH * nD * 2);  // B*S*KV*D
  bf16* v = k + (size_t)nB * nS * nKV * nD;
  bf16* att = v + (size_t)nB * nS * nKV * nD;  // B*S*H*D
  float* out = (float*)d_out;

  const int M = nB * nS;
  gemm_proj<<<dim3(nH * nD / 64, M / 64), 256, 0, stream>>>(hs, Wq, q, M, nH * nD, nHID);
  gemm_proj<<<dim3(nKV * nD / 64, M / 64), 256, 0, stream>>>(hs, Wk, k, M, nKV * nD, nHID);
  gemm_proj<<<dim3(nKV * nD / 64, M / 64), 256, 0, stream>>>(hs, Wv, v, M, nKV * nD, nHID);
  norm_rope_kernel<<<dim3(M, nH), 128, 0, stream>>>(q, qw, nH);
  norm_rope_kernel<<<dim3(M, nKV), 128, 0, stream>>>(k, kw, nKV);
  attn_mfma<<<dim3(nS / BQ, nB * nH), 256, 0, stream>>>(q, k, v, att);
  gemm_out<<<dim3(nHID / 64, M / 64), 256, 0, stream>>>(att, Wo, out, M, nHID, nH * nD);
}

// Round 4
// 469.332 us; speedup vs baseline: 21.7321x; 3.3921x over previous
//
#include <hip/hip_runtime.h>
#include <hip/hip_bf16.h>

typedef __hip_bfloat16 bf16;
typedef __attribute__((ext_vector_type(8))) short short8v;
typedef __attribute__((ext_vector_type(4))) float f32x4;

constexpr int nB = 2;
constexpr int nS = 2048;
constexpr int nHID = 2048;
constexpr int nH = 16;
constexpr int nKV = 8;
constexpr int nD = 128;
constexpr float kEps = 1e-6f;
constexpr float kScale = 0.08838834764831845f;  // 1/sqrt(128)

__device__ inline float b2f(unsigned short u) {
  return __uint_as_float(((unsigned)u) << 16);
}
__device__ inline float bf2f(bf16 v) { return __bfloat162float(v); }
__device__ inline short f2bs(float f) {
  bf16 h = __float2bfloat16(f);
  return *reinterpret_cast<short*>(&h);
}

__device__ inline void gload_lds16(const bf16* g, bf16* l) {
  __builtin_amdgcn_global_load_lds(
      (const __attribute__((address_space(1))) void*)g,
      (__attribute__((address_space(3))) void*)l, 16, 0, 0);
}

// ---------------------------------------------------------------------------
// fp32 -> bf16 elementwise convert (n multiple of 4)
// ---------------------------------------------------------------------------
__global__ __launch_bounds__(256) void cvt_f32_bf16(
    const float* __restrict__ src, bf16* __restrict__ dst, int n) {
  const int i = (blockIdx.x * 256 + threadIdx.x) * 4;
  if (i >= n) return;
  const float4 v = *reinterpret_cast<const float4*>(src + i);
  ushort4 o;
  o.x = (unsigned short)f2bs(v.x);
  o.y = (unsigned short)f2bs(v.y);
  o.z = (unsigned short)f2bs(v.z);
  o.w = (unsigned short)f2bs(v.w);
  *reinterpret_cast<ushort4*>(dst + i) = o;
}

// ---------------------------------------------------------------------------
// Transpose + convert: src[K][N] fp32 -> dst[N][K] bf16. 32x32 tiles.
// ---------------------------------------------------------------------------
__global__ __launch_bounds__(256) void transpose_f32_bf16(
    const float* __restrict__ src, bf16* __restrict__ dst, int K, int N) {
  __shared__ float t[32][33];
  const int k0 = blockIdx.y * 32, n0 = blockIdx.x * 32;
  const int c = threadIdx.x & 31, r8 = threadIdx.x >> 5;  // 8 rows/pass
#pragma unroll
  for (int i = 0; i < 4; ++i)
    t[r8 + i * 8][c] = src[(size_t)(k0 + r8 + i * 8) * N + n0 + c];
  __syncthreads();
#pragma unroll
  for (int i = 0; i < 4; ++i)
    dst[(size_t)(n0 + r8 + i * 8) * K + k0 + c] =
        __float2bfloat16(t[c][r8 + i * 8]);
}

// ---------------------------------------------------------------------------
// bf16 MFMA GEMM (m97 structure): C[M][N] = A[M][K] @ Bt[N][K]^T
// 128x128 tile, BK=64, 256 threads = 4 waves (2x2), 4x4 16x16 frags/wave.
// LDS linear [128 rows][64 k] per operand; global source pre-swizzled
// chunk^row so ds_read (same XOR) is bank-conflict-free (rule #21 pair).
// ---------------------------------------------------------------------------
template <typename OUT_T>
__global__ __launch_bounds__(256) void gemm_mfma(
    const bf16* __restrict__ A, const bf16* __restrict__ Bt,
    OUT_T* __restrict__ C, int M, int N, int K) {
  __shared__ bf16 As[128 * 64];
  __shared__ bf16 Bs[128 * 64];
  const int tid = threadIdx.x;
  const int wave = tid >> 6, lane = tid & 63;
  const int lr = lane & 15, lg = lane >> 4;
  const int wm = wave >> 1, wn = wave & 1;
  const int m0 = blockIdx.y * 128, n0 = blockIdx.x * 128;

  // staging coords: lane covers LDS bytes [lane*16, lane*16+16) of its wave's
  // 1KB region (8 rows x 8 chunks). Source chunk is XOR-swizzled by row.
  const int srow = lane >> 3;            // row within 8-row group
  const int schunk = (lane & 7) ^ srow;  // pre-swizzled source chunk
  const bf16* aP = A + (size_t)(m0 + wave * 8 + srow) * K + schunk * 8;
  const bf16* bP = Bt + (size_t)(n0 + wave * 8 + srow) * K + schunk * 8;
  bf16* asW = As + (size_t)(wave * 8) * 64;  // wave-uniform LDS bases
  bf16* bsW = Bs + (size_t)(wave * 8) * 64;

  f32x4 acc[4][4];
#pragma unroll
  for (int m = 0; m < 4; ++m)
#pragma unroll
    for (int n = 0; n < 4; ++n) acc[m][n] = (f32x4){0.f, 0.f, 0.f, 0.f};

  for (int kt = 0; kt < K; kt += 64) {
    __syncthreads();  // previous tile consumed
#pragma unroll
    for (int j = 0; j < 4; ++j) {
      gload_lds16(aP + (size_t)j * 32 * K + kt, asW + j * 32 * 64);
      gload_lds16(bP + (size_t)j * 32 * K + kt, bsW + j * 32 * 64);
    }
    __syncthreads();  // compiler emits vmcnt(0) before barrier
#pragma unroll
    for (int kk = 0; kk < 2; ++kk) {
      short8v af[4], bfr[4];
#pragma unroll
      for (int m = 0; m < 4; ++m) {
        const int r = 64 * wm + 16 * m + lr;
        const int c = (kk * 4 + lg) ^ (lr & 7);
        af[m] = *reinterpret_cast<const short8v*>(&As[r * 64 + c * 8]);
      }
#pragma unroll
      for (int n = 0; n < 4; ++n) {
        const int r = 64 * wn + 16 * n + lr;
        const int c = (kk * 4 + lg) ^ (lr & 7);
        bfr[n] = *reinterpret_cast<const short8v*>(&Bs[r * 64 + c * 8]);
      }
#pragma unroll
      for (int m = 0; m < 4; ++m)
#pragma unroll
        for (int n = 0; n < 4; ++n)
          acc[m][n] = __builtin_amdgcn_mfma_f32_16x16x32_bf16(
              af[m], bfr[n], acc[m][n], 0, 0, 0);
    }
  }

#pragma unroll
  for (int m = 0; m < 4; ++m)
#pragma unroll
    for (int n = 0; n < 4; ++n)
#pragma unroll
      for (int r = 0; r < 4; ++r) {
        const int row = m0 + 64 * wm + 16 * m + 4 * lg + r;
        const int col = n0 + 64 * wn + 16 * n + lr;
        if constexpr (sizeof(OUT_T) == 2)
          C[(size_t)row * N + col] = __float2bfloat16(acc[m][n][r]);
        else
          C[(size_t)row * N + col] = acc[m][n][r];
      }
}

// ---------------------------------------------------------------------------
// Per-head RMSNorm + RoPE, in place on bf16.
// ---------------------------------------------------------------------------
__global__ __launch_bounds__(128) void norm_rope_kernel(
    bf16* __restrict__ x, const float* __restrict__ w, int NHd) {
  const int row = blockIdx.x;  // b*S + s
  const int head = blockIdx.y;
  const int t = threadIdx.x;  // 0..127 = head dim
  const int s = row & (nS - 1);
  bf16* xp = x + ((size_t)row * NHd + head) * nD;
  const float v = bf2f(xp[t]);
  float ss = v * v;
#pragma unroll
  for (int off = 32; off > 0; off >>= 1) ss += __shfl_xor(ss, off);
  __shared__ float wsum[2];
  __shared__ float buf[nD];
  if ((t & 63) == 0) wsum[t >> 6] = ss;
  __syncthreads();
  const float inv = rsqrtf((wsum[0] + wsum[1]) * (1.0f / nD) + kEps);
  const float nv = v * inv * w[t];
  buf[t] = nv;
  __syncthreads();
  const float partner = buf[t ^ 64];
  const float rot = (t < 64) ? -partner : partner;
  const int j = t & 63;
  const float invf = expf(-(float)j * (13.815510557964274f / 64.0f));
  const float ang = (float)s * invf;
  const float outv = nv * cosf(ang) + rot * sinf(ang);
  xp[t] = __float2bfloat16(outv);
}

// ---------------------------------------------------------------------------
// MFMA causal GQA flash attention (unchanged from round 2).
// ---------------------------------------------------------------------------
constexpr int BQ = 64, BKT = 64;

__global__ __launch_bounds__(256) void attn_mfma(
    const bf16* __restrict__ Q, const bf16* __restrict__ Kg,
    const bf16* __restrict__ Vg, bf16* __restrict__ O) {
  const int qb = (int)gridDim.x - 1 - (int)blockIdx.x;  // heavy blocks first
  const int q0 = qb * BQ;
  const int bh = blockIdx.y;
  const int b = bh >> 4, h = bh & 15, kvh = h >> 1;
  const int tid = threadIdx.x;
  const int wave = tid >> 6, lane = tid & 63;
  const int lr = lane & 15, lg = lane >> 4;

  __shared__ bf16 Ks[BKT][136];
  __shared__ bf16 Vt[nD][72];
  __shared__ bf16 Pl[4][16][72];

  short8v qf[4];
  {
    const bf16* qrow =
        Q + ((size_t)(b * nS + q0 + 16 * wave + lr) * nH + h) * nD;
#pragma unroll
    for (int dc = 0; dc < 4; ++dc)
      qf[dc] = *reinterpret_cast<const short8v*>(qrow + 32 * dc + 8 * lg);
  }

  const bf16* Kbase = Kg + (size_t)b * nS * (nKV * nD) + (size_t)kvh * nD;
  const bf16* Vbase = Vg + (size_t)b * nS * (nKV * nD) + (size_t)kvh * nD;

  f32x4 of[8];
#pragma unroll
  for (int n = 0; n < 8; ++n) of[n] = (f32x4){0.f, 0.f, 0.f, 0.f};
  float mrow[4] = {-1e30f, -1e30f, -1e30f, -1e30f};
  float lrow[4] = {0.f, 0.f, 0.f, 0.f};

  const int krow = tid >> 2, kcc = (tid & 3) * 32;
  const int vkey = tid & 63, vdc = (tid >> 6) * 32;

  for (int kt0 = 0; kt0 <= q0; kt0 += BKT) {
    __syncthreads();
    {
      const bf16* src = Kbase + (size_t)(kt0 + krow) * (nKV * nD) + kcc;
#pragma unroll
      for (int i = 0; i < 4; ++i)
        *reinterpret_cast<short8v*>(&Ks[krow][kcc + 8 * i]) =
            *reinterpret_cast<const short8v*>(src + 8 * i);
    }
    {
      const bf16* src = Vbase + (size_t)(kt0 + vkey) * (nKV * nD) + vdc;
#pragma unroll
      for (int i = 0; i < 4; ++i) {
        const short8v v = *reinterpret_cast<const short8v*>(src + 8 * i);
#pragma unroll
        for (int j = 0; j < 8; ++j)
          *reinterpret_cast<short*>(&Vt[vdc + 8 * i + j][vkey]) = v[j];
      }
    }
    __syncthreads();

    f32x4 sfr[4];
#pragma unroll
    for (int sub = 0; sub < 4; ++sub) {
      f32x4 acc = {0.f, 0.f, 0.f, 0.f};
#pragma unroll
      for (int dc = 0; dc < 4; ++dc) {
        const short8v kf = *reinterpret_cast<const short8v*>(
            &Ks[16 * sub + lr][32 * dc + 8 * lg]);
        acc = __builtin_amdgcn_mfma_f32_16x16x32_bf16(qf[dc], kf, acc, 0, 0, 0);
      }
      sfr[sub] = acc;
    }

    const bool diag = (kt0 == q0);
#pragma unroll
    for (int sub = 0; sub < 4; ++sub)
#pragma unroll
      for (int r = 0; r < 4; ++r) {
        float s = sfr[sub][r] * kScale;
        if (diag && (16 * sub + lr > 16 * wave + 4 * lg + r)) s = -1e30f;
        sfr[sub][r] = s;
      }

    float mt[4];
#pragma unroll
    for (int r = 0; r < 4; ++r) {
      float v = fmaxf(fmaxf(sfr[0][r], sfr[1][r]), fmaxf(sfr[2][r], sfr[3][r]));
#pragma unroll
      for (int off = 1; off < 16; off <<= 1) v = fmaxf(v, __shfl_xor(v, off));
      mt[r] = fmaxf(mrow[r], v);
    }
#pragma unroll
    for (int sub = 0; sub < 4; ++sub)
#pragma unroll
      for (int r = 0; r < 4; ++r) sfr[sub][r] = __expf(sfr[sub][r] - mt[r]);
#pragma unroll
    for (int r = 0; r < 4; ++r) {
      float ps = sfr[0][r] + sfr[1][r] + sfr[2][r] + sfr[3][r];
#pragma unroll
      for (int off = 1; off < 16; off <<= 1) ps += __shfl_xor(ps, off);
      const float corr = __expf(mrow[r] - mt[r]);
      lrow[r] = lrow[r] * corr + ps;
      mrow[r] = mt[r];
#pragma unroll
      for (int n = 0; n < 8; ++n) of[n][r] *= corr;
    }

#pragma unroll
    for (int sub = 0; sub < 4; ++sub)
#pragma unroll
      for (int r = 0; r < 4; ++r)
        *reinterpret_cast<short*>(&Pl[wave][4 * lg + r][16 * sub + lr]) =
            f2bs(sfr[sub][r]);

    short8v pa[2];
#pragma unroll
    for (int c = 0; c < 2; ++c)
      pa[c] =
          *reinterpret_cast<const short8v*>(&Pl[wave][lr][32 * c + 8 * lg]);
#pragma unroll
    for (int n = 0; n < 8; ++n)
#pragma unroll
      for (int c = 0; c < 2; ++c) {
        const short8v vf = *reinterpret_cast<const short8v*>(
            &Vt[16 * n + lr][32 * c + 8 * lg]);
        of[n] =
            __builtin_amdgcn_mfma_f32_16x16x32_bf16(pa[c], vf, of[n], 0, 0, 0);
      }
  }

#pragma unroll
  for (int r = 0; r < 4; ++r) {
    const float inv = 1.0f / lrow[r];
    bf16* orow =
        O + ((size_t)(b * nS + q0 + 16 * wave + 4 * lg + r) * nH + h) * nD;
#pragma unroll
    for (int n = 0; n < 8; ++n)
      orow[16 * n + lr] = __float2bfloat16(of[n][r] * inv);
  }
}

// ---------------------------------------------------------------------------
extern "C" void kernel_launch(void* const* d_in, const int* in_sizes, int n_in,
                              void* d_out, int out_size, void* d_ws,
                              size_t ws_size, hipStream_t stream) {
  const float* hs = (const float*)d_in[0];
  const float* Wq = (const float*)d_in[1];
  const float* Wk = (const float*)d_in[2];
  const float* Wv = (const float*)d_in[3];
  const float* Wo = (const float*)d_in[4];
  const float* qw = (const float*)d_in[5];
  const float* kw = (const float*)d_in[6];

  const int M = nB * nS;  // 4096
  char* ws = (char*)d_ws;
  size_t off = 0;
  auto alloc = [&](size_t bytes) {
    char* p = ws + off;
    off += bytes;
    return p;
  };
  bf16* q = (bf16*)alloc((size_t)M * nH * nD * 2);    // 16.8 MB
  bf16* k = (bf16*)alloc((size_t)M * nKV * nD * 2);   // 8.4 MB
  bf16* v = (bf16*)alloc((size_t)M * nKV * nD * 2);   // 8.4 MB
  bf16* hsb = (bf16*)alloc((size_t)M * nHID * 2);     // 16.8 MB (att aliases)
  bf16* att = hsb;                                    // reused after projs
  bf16* Wqt = (bf16*)alloc((size_t)nHID * nH * nD * 2);
  bf16* Wkt = (bf16*)alloc((size_t)nHID * nKV * nD * 2);
  bf16* Wvt = (bf16*)alloc((size_t)nHID * nKV * nD * 2);
  bf16* Wot = (bf16*)alloc((size_t)nH * nD * nHID * 2);
  float* out = (float*)d_out;

  const int nHsElems = M * nHID;
  cvt_f32_bf16<<<(nHsElems / 4 + 255) / 256, 256, 0, stream>>>(hs, hsb,
                                                               nHsElems);
  transpose_f32_bf16<<<dim3(nH * nD / 32, nHID / 32), 256, 0, stream>>>(
      Wq, Wqt, nHID, nH * nD);
  transpose_f32_bf16<<<dim3(nKV * nD / 32, nHID / 32), 256, 0, stream>>>(
      Wk, Wkt, nHID, nKV * nD);
  transpose_f32_bf16<<<dim3(nKV * nD / 32, nHID / 32), 256, 0, stream>>>(
      Wv, Wvt, nHID, nKV * nD);
  transpose_f32_bf16<<<dim3(nHID / 32, nH * nD / 32), 256, 0, stream>>>(
      Wo, Wot, nH * nD, nHID);

  gemm_mfma<bf16><<<dim3(nH * nD / 128, M / 128), 256, 0, stream>>>(
      hsb, Wqt, q, M, nH * nD, nHID);
  gemm_mfma<bf16><<<dim3(nKV * nD / 128, M / 128), 256, 0, stream>>>(
      hsb, Wkt, k, M, nKV * nD, nHID);
  gemm_mfma<bf16><<<dim3(nKV * nD / 128, M / 128), 256, 0, stream>>>(
      hsb, Wvt, v, M, nKV * nD, nHID);

  norm_rope_kernel<<<dim3(M, nH), 128, 0, stream>>>(q, qw, nH);
  norm_rope_kernel<<<dim3(M, nKV), 128, 0, stream>>>(k, kw, nKV);

  attn_mfma<<<dim3(nS / BQ, nB * nH), 256, 0, stream>>>(q, k, v, att);

  gemm_mfma<float><<<dim3(nHID / 128, M / 128), 256, 0, stream>>>(
      att, Wot, out, M, nHID, nH * nD);
}

// Round 5
// 325.637 us; speedup vs baseline: 31.3220x; 1.4413x over previous
//
#include <hip/hip_runtime.h>
#include <hip/hip_bf16.h>

typedef __hip_bfloat16 bf16;
typedef __attribute__((ext_vector_type(8))) short short8v;
typedef __attribute__((ext_vector_type(4))) float f32x4;

constexpr int nB = 2;
constexpr int nS = 2048;
constexpr int nHID = 2048;
constexpr int nH = 16;
constexpr int nKV = 8;
constexpr int nD = 128;
constexpr float kEps = 1e-6f;
constexpr float kScale = 0.08838834764831845f;  // 1/sqrt(128)

__device__ inline float b2f(unsigned short u) {
  return __uint_as_float(((unsigned)u) << 16);
}
__device__ inline float bf2f(bf16 v) { return __bfloat162float(v); }
__device__ inline short f2bs(float f) {
  bf16 h = __float2bfloat16(f);
  return *reinterpret_cast<short*>(&h);
}
__device__ inline unsigned pack2bf(float a, float b) {
  return ((unsigned)(unsigned short)f2bs(b) << 16) |
         (unsigned)(unsigned short)f2bs(a);
}

__device__ inline void gload_lds16(const bf16* g, bf16* l) {
  __builtin_amdgcn_global_load_lds(
      (const __attribute__((address_space(1))) void*)g,
      (__attribute__((address_space(3))) void*)l, 16, 0, 0);
}

// ---------------------------------------------------------------------------
// fp32 -> bf16 elementwise convert (n multiple of 4)
// ---------------------------------------------------------------------------
__global__ __launch_bounds__(256) void cvt_f32_bf16(
    const float* __restrict__ src, bf16* __restrict__ dst, int n) {
  const int i = (blockIdx.x * 256 + threadIdx.x) * 4;
  if (i >= n) return;
  const float4 v = *reinterpret_cast<const float4*>(src + i);
  ushort4 o;
  o.x = (unsigned short)f2bs(v.x);
  o.y = (unsigned short)f2bs(v.y);
  o.z = (unsigned short)f2bs(v.z);
  o.w = (unsigned short)f2bs(v.w);
  *reinterpret_cast<ushort4*>(dst + i) = o;
}

// ---------------------------------------------------------------------------
// Transpose + convert: src[K][N] fp32 -> dst[N][K] bf16. 32x32 tiles.
// ---------------------------------------------------------------------------
__global__ __launch_bounds__(256) void transpose_f32_bf16(
    const float* __restrict__ src, bf16* __restrict__ dst, int K, int N) {
  __shared__ float t[32][33];
  const int k0 = blockIdx.y * 32, n0 = blockIdx.x * 32;
  const int c = threadIdx.x & 31, r8 = threadIdx.x >> 5;
#pragma unroll
  for (int i = 0; i < 4; ++i)
    t[r8 + i * 8][c] = src[(size_t)(k0 + r8 + i * 8) * N + n0 + c];
  __syncthreads();
#pragma unroll
  for (int i = 0; i < 4; ++i)
    dst[(size_t)(n0 + r8 + i * 8) * K + k0 + c] =
        __float2bfloat16(t[c][r8 + i * 8]);
}

// ---------------------------------------------------------------------------
// bf16 MFMA GEMM (m97 structure): C[M][N] = A[M][K] @ Bt[N][K]^T
// (unchanged from round 3 — verified)
// ---------------------------------------------------------------------------
template <typename OUT_T>
__global__ __launch_bounds__(256) void gemm_mfma(
    const bf16* __restrict__ A, const bf16* __restrict__ Bt,
    OUT_T* __restrict__ C, int M, int N, int K) {
  __shared__ bf16 As[128 * 64];
  __shared__ bf16 Bs[128 * 64];
  const int tid = threadIdx.x;
  const int wave = tid >> 6, lane = tid & 63;
  const int lr = lane & 15, lg = lane >> 4;
  const int wm = wave >> 1, wn = wave & 1;
  const int m0 = blockIdx.y * 128, n0 = blockIdx.x * 128;

  const int srow = lane >> 3;
  const int schunk = (lane & 7) ^ srow;
  const bf16* aP = A + (size_t)(m0 + wave * 8 + srow) * K + schunk * 8;
  const bf16* bP = Bt + (size_t)(n0 + wave * 8 + srow) * K + schunk * 8;
  bf16* asW = As + (size_t)(wave * 8) * 64;
  bf16* bsW = Bs + (size_t)(wave * 8) * 64;

  f32x4 acc[4][4];
#pragma unroll
  for (int m = 0; m < 4; ++m)
#pragma unroll
    for (int n = 0; n < 4; ++n) acc[m][n] = (f32x4){0.f, 0.f, 0.f, 0.f};

  for (int kt = 0; kt < K; kt += 64) {
    __syncthreads();
#pragma unroll
    for (int j = 0; j < 4; ++j) {
      gload_lds16(aP + (size_t)j * 32 * K + kt, asW + j * 32 * 64);
      gload_lds16(bP + (size_t)j * 32 * K + kt, bsW + j * 32 * 64);
    }
    __syncthreads();
#pragma unroll
    for (int kk = 0; kk < 2; ++kk) {
      short8v af[4], bfr[4];
#pragma unroll
      for (int m = 0; m < 4; ++m) {
        const int r = 64 * wm + 16 * m + lr;
        const int c = (kk * 4 + lg) ^ (lr & 7);
        af[m] = *reinterpret_cast<const short8v*>(&As[r * 64 + c * 8]);
      }
#pragma unroll
      for (int n = 0; n < 4; ++n) {
        const int r = 64 * wn + 16 * n + lr;
        const int c = (kk * 4 + lg) ^ (lr & 7);
        bfr[n] = *reinterpret_cast<const short8v*>(&Bs[r * 64 + c * 8]);
      }
#pragma unroll
      for (int m = 0; m < 4; ++m)
#pragma unroll
        for (int n = 0; n < 4; ++n)
          acc[m][n] = __builtin_amdgcn_mfma_f32_16x16x32_bf16(
              af[m], bfr[n], acc[m][n], 0, 0, 0);
    }
  }

#pragma unroll
  for (int m = 0; m < 4; ++m)
#pragma unroll
    for (int n = 0; n < 4; ++n)
#pragma unroll
      for (int r = 0; r < 4; ++r) {
        const int row = m0 + 64 * wm + 16 * m + 4 * lg + r;
        const int col = n0 + 64 * wn + 16 * n + lr;
        if constexpr (sizeof(OUT_T) == 2)
          C[(size_t)row * N + col] = __float2bfloat16(acc[m][n][r]);
        else
          C[(size_t)row * N + col] = acc[m][n][r];
      }
}

// ---------------------------------------------------------------------------
// Per-head RMSNorm + RoPE, in place on bf16.
// ---------------------------------------------------------------------------
__global__ __launch_bounds__(128) void norm_rope_kernel(
    bf16* __restrict__ x, const float* __restrict__ w, int NHd) {
  const int row = blockIdx.x;
  const int head = blockIdx.y;
  const int t = threadIdx.x;
  const int s = row & (nS - 1);
  bf16* xp = x + ((size_t)row * NHd + head) * nD;
  const float v = bf2f(xp[t]);
  float ss = v * v;
#pragma unroll
  for (int off = 32; off > 0; off >>= 1) ss += __shfl_xor(ss, off);
  __shared__ float wsum[2];
  __shared__ float buf[nD];
  if ((t & 63) == 0) wsum[t >> 6] = ss;
  __syncthreads();
  const float inv = rsqrtf((wsum[0] + wsum[1]) * (1.0f / nD) + kEps);
  const float nv = v * inv * w[t];
  buf[t] = nv;
  __syncthreads();
  const float partner = buf[t ^ 64];
  const float rot = (t < 64) ? -partner : partner;
  const int j = t & 63;
  const float invf = expf(-(float)j * (13.815510557964274f / 64.0f));
  const float ang = (float)s * invf;
  const float outv = nv * cosf(ang) + rot * sinf(ang);
  xp[t] = __float2bfloat16(outv);
}

// ---------------------------------------------------------------------------
// MFMA causal GQA flash attention, round-5 structure:
//   - swapped QK^T (S^T = mfma(K,Q)): lane owns column q=lr; softmax reduce
//     = in-reg over 16 + 2 shuffles; ONE corr per lane.
//   - PV as O^T = mfma(Vt-frag, P-frag); P packed to Pl[q][k] as 8 b32.
//   - T14 async staging: next tile's global loads issued before compute.
//   - paired q-tiles (i, 31-i): 512 blocks x exactly 33 tiles (balanced).
//   - T13 defer-rescale (THR=8), T5 setprio around MFMA.
// ---------------------------------------------------------------------------
constexpr int BQ = 64, BKT = 64;

__global__ __launch_bounds__(256) void attn_mfma(
    const bf16* __restrict__ Q, const bf16* __restrict__ Kg,
    const bf16* __restrict__ Vg, bf16* __restrict__ O) {
  const int pair = blockIdx.x;  // 0..15
  const int bh = blockIdx.y;
  const int b = bh >> 4, h = bh & 15, kvh = h >> 1;
  const int tid = threadIdx.x;
  const int wave = tid >> 6, lane = tid & 63;
  const int lr = lane & 15, lg = lane >> 4;

  __shared__ bf16 Ks[BKT][136];   // row-major K tile (+8 pad)
  __shared__ bf16 Vt[nD][72];     // transposed V tile
  __shared__ bf16 Pl[4][16][72];  // per-wave P, layout [q][k]

  const bf16* Kbase = Kg + (size_t)b * nS * (nKV * nD) + (size_t)kvh * nD;
  const bf16* Vbase = Vg + (size_t)b * nS * (nKV * nD) + (size_t)kvh * nD;

  const int krow = tid >> 2, kcc = (tid & 3) * 32;
  const int vkey = tid & 63, vdc = (tid >> 6) * 32;

  short8v kreg[4], vreg[4];  // T14 in-flight staging registers
  auto gload = [&](int kt) {
    const bf16* ksrc = Kbase + (size_t)(kt + krow) * (nKV * nD) + kcc;
    const bf16* vsrc = Vbase + (size_t)(kt + vkey) * (nKV * nD) + vdc;
#pragma unroll
    for (int i = 0; i < 4; ++i) {
      kreg[i] = *reinterpret_cast<const short8v*>(ksrc + 8 * i);
      vreg[i] = *reinterpret_cast<const short8v*>(vsrc + 8 * i);
    }
  };
  auto lwrite = [&]() {
#pragma unroll
    for (int i = 0; i < 4; ++i)
      *reinterpret_cast<short8v*>(&Ks[krow][kcc + 8 * i]) = kreg[i];
#pragma unroll
    for (int i = 0; i < 4; ++i)
#pragma unroll
      for (int j = 0; j < 8; ++j)
        *reinterpret_cast<short*>(&Vt[vdc + 8 * i + j][vkey]) = vreg[i][j];
  };

  short8v qf[4];
  f32x4 of[8];
  float m_run, l_run;

  auto load_q = [&](int q0) {
    const bf16* qrow =
        Q + ((size_t)(b * nS + q0 + 16 * wave + lr) * nH + h) * nD;
#pragma unroll
    for (int dc = 0; dc < 4; ++dc)
      qf[dc] = *reinterpret_cast<const short8v*>(qrow + 32 * dc + 8 * lg);
  };

  auto run_tiles = [&](int q0, int nt, bool stage_next0) {
    m_run = -1e30f;
    l_run = 0.f;
#pragma unroll
    for (int n = 0; n < 8; ++n) of[n] = (f32x4){0.f, 0.f, 0.f, 0.f};
    for (int j = 0; j < nt; ++j) {
      const int kt = j * BKT;
      const bool have_next = (j + 1 < nt) || stage_next0;
      const int ktn = (j + 1 < nt) ? (j + 1) * BKT : 0;
      if (have_next) gload(ktn);  // T14: issue early, write after barrier

      // ---- QK^T swapped: S^T[k=16sub+4lg+r][q=lr]
      f32x4 s[4];
      __builtin_amdgcn_s_setprio(1);
#pragma unroll
      for (int sub = 0; sub < 4; ++sub) {
        f32x4 acc = {0.f, 0.f, 0.f, 0.f};
#pragma unroll
        for (int dc = 0; dc < 4; ++dc) {
          const short8v kf = *reinterpret_cast<const short8v*>(
              &Ks[16 * sub + lr][32 * dc + 8 * lg]);
          acc = __builtin_amdgcn_mfma_f32_16x16x32_bf16(kf, qf[dc], acc, 0, 0,
                                                        0);
        }
        s[sub] = acc;
      }
      __builtin_amdgcn_s_setprio(0);

      // ---- scale + causal mask (diagonal tile only)
      const bool diag = (kt == q0);
#pragma unroll
      for (int sub = 0; sub < 4; ++sub)
#pragma unroll
        for (int r = 0; r < 4; ++r) {
          float v = s[sub][r] * kScale;
          if (diag && (16 * sub + 4 * lg + r > 16 * wave + lr)) v = -1e30f;
          s[sub][r] = v;
        }

      // ---- online softmax, column q = lr (shared by lanes lr, lr+16,+32,+48)
      float pmax = -1e30f;
#pragma unroll
      for (int sub = 0; sub < 4; ++sub)
#pragma unroll
        for (int r = 0; r < 4; ++r) pmax = fmaxf(pmax, s[sub][r]);
      pmax = fmaxf(pmax, __shfl_xor(pmax, 16));
      pmax = fmaxf(pmax, __shfl_xor(pmax, 32));

      if (!__all(pmax - m_run <= 8.f)) {  // T13 defer-rescale
        const float mt = fmaxf(m_run, pmax);
        const float corr = __expf(m_run - mt);
#pragma unroll
        for (int n = 0; n < 8; ++n) of[n] *= corr;
        l_run *= corr;
        m_run = mt;
      }

      float p[4][4];
      float lsum = 0.f;
#pragma unroll
      for (int sub = 0; sub < 4; ++sub)
#pragma unroll
        for (int r = 0; r < 4; ++r) {
          const float e = __expf(s[sub][r] - m_run);
          p[sub][r] = e;
          lsum += e;
        }
      lsum += __shfl_xor(lsum, 16);
      lsum += __shfl_xor(lsum, 32);
      l_run += lsum;

      // ---- P -> Pl[q][k]: 8 packed b32 writes
#pragma unroll
      for (int sub = 0; sub < 4; ++sub)
#pragma unroll
        for (int rp = 0; rp < 2; ++rp)
          *reinterpret_cast<unsigned*>(
              &Pl[wave][lr][16 * sub + 4 * lg + 2 * rp]) =
              pack2bf(p[sub][2 * rp], p[sub][2 * rp + 1]);

      // ---- PV as O^T: of[n] holds O^T[d=16n+4lg+r][q=lr]
      __builtin_amdgcn_s_setprio(1);
#pragma unroll
      for (int kk = 0; kk < 2; ++kk) {
        const short8v pb = *reinterpret_cast<const short8v*>(
            &Pl[wave][lr][32 * kk + 8 * lg]);
#pragma unroll
        for (int n = 0; n < 8; ++n) {
          const short8v vf = *reinterpret_cast<const short8v*>(
              &Vt[16 * n + lr][32 * kk + 8 * lg]);
          of[n] =
              __builtin_amdgcn_mfma_f32_16x16x32_bf16(vf, pb, of[n], 0, 0, 0);
        }
      }
      __builtin_amdgcn_s_setprio(0);

      if (have_next) {
        __syncthreads();  // all waves done reading Ks/Vt of tile j
        lwrite();
        __syncthreads();  // next tile visible
      }
    }
  };

  auto epilogue = [&](int q0) {
    const float inv = 1.0f / l_run;
    bf16* orow =
        O + ((size_t)(b * nS + q0 + 16 * wave + lr) * nH + h) * nD + 4 * lg;
#pragma unroll
    for (int n = 0; n < 8; ++n)
#pragma unroll
      for (int rp = 0; rp < 2; ++rp)
        *reinterpret_cast<unsigned*>(orow + 16 * n + 2 * rp) =
            pack2bf(of[n][2 * rp] * inv, of[n][2 * rp + 1] * inv);
  };

  // paired q-tiles: heavy (31-pair) then light (pair): 33 tiles total/block
  const int qh = (31 - pair) * BQ, nth = 32 - pair;
  const int ql = pair * BQ, ntl = pair + 1;

  gload(0);
  lwrite();
  __syncthreads();  // prologue: tile 0 staged

  load_q(qh);
  run_tiles(qh, nth, true);  // last iter stages light's tile 0
  epilogue(qh);

  load_q(ql);
  run_tiles(ql, ntl, false);
  epilogue(ql);
}

// ---------------------------------------------------------------------------
extern "C" void kernel_launch(void* const* d_in, const int* in_sizes, int n_in,
                              void* d_out, int out_size, void* d_ws,
                              size_t ws_size, hipStream_t stream) {
  const float* hs = (const float*)d_in[0];
  const float* Wq = (const float*)d_in[1];
  const float* Wk = (const float*)d_in[2];
  const float* Wv = (const float*)d_in[3];
  const float* Wo = (const float*)d_in[4];
  const float* qw = (const float*)d_in[5];
  const float* kw = (const float*)d_in[6];

  const int M = nB * nS;  // 4096
  char* ws = (char*)d_ws;
  size_t off = 0;
  auto alloc = [&](size_t bytes) {
    char* p = ws + off;
    off += bytes;
    return p;
  };
  bf16* q = (bf16*)alloc((size_t)M * nH * nD * 2);
  bf16* k = (bf16*)alloc((size_t)M * nKV * nD * 2);
  bf16* v = (bf16*)alloc((size_t)M * nKV * nD * 2);
  bf16* hsb = (bf16*)alloc((size_t)M * nHID * 2);
  bf16* att = hsb;  // reused after projections
  bf16* Wqt = (bf16*)alloc((size_t)nHID * nH * nD * 2);
  bf16* Wkt = (bf16*)alloc((size_t)nHID * nKV * nD * 2);
  bf16* Wvt = (bf16*)alloc((size_t)nHID * nKV * nD * 2);
  bf16* Wot = (bf16*)alloc((size_t)nH * nD * nHID * 2);
  float* out = (float*)d_out;

  const int nHsElems = M * nHID;
  cvt_f32_bf16<<<(nHsElems / 4 + 255) / 256, 256, 0, stream>>>(hs, hsb,
                                                               nHsElems);
  transpose_f32_bf16<<<dim3(nH * nD / 32, nHID / 32), 256, 0, stream>>>(
      Wq, Wqt, nHID, nH * nD);
  transpose_f32_bf16<<<dim3(nKV * nD / 32, nHID / 32), 256, 0, stream>>>(
      Wk, Wkt, nHID, nKV * nD);
  transpose_f32_bf16<<<dim3(nKV * nD / 32, nHID / 32), 256, 0, stream>>>(
      Wv, Wvt, nHID, nKV * nD);
  transpose_f32_bf16<<<dim3(nHID / 32, nH * nD / 32), 256, 0, stream>>>(
      Wo, Wot, nH * nD, nHID);

  gemm_mfma<bf16><<<dim3(nH * nD / 128, M / 128), 256, 0, stream>>>(
      hsb, Wqt, q, M, nH * nD, nHID);
  gemm_mfma<bf16><<<dim3(nKV * nD / 128, M / 128), 256, 0, stream>>>(
      hsb, Wkt, k, M, nKV * nD, nHID);
  gemm_mfma<bf16><<<dim3(nKV * nD / 128, M / 128), 256, 0, stream>>>(
      hsb, Wvt, v, M, nKV * nD, nHID);

  norm_rope_kernel<<<dim3(M, nH), 128, 0, stream>>>(q, qw, nH);
  norm_rope_kernel<<<dim3(M, nKV), 128, 0, stream>>>(k, kw, nKV);

  attn_mfma<<<dim3(16, nB * nH), 256, 0, stream>>>(q, k, v, att);

  gemm_mfma<float><<<dim3(nHID / 128, M / 128), 256, 0, stream>>>(
      att, Wot, out, M, nHID, nH * nD);
}

// Round 6
// 285.563 us; speedup vs baseline: 35.7175x; 1.1403x over previous
//
#include <hip/hip_runtime.h>
#include <hip/hip_bf16.h>

typedef __hip_bfloat16 bf16;
typedef __attribute__((ext_vector_type(8))) short short8v;
typedef __attribute__((ext_vector_type(4))) float f32x4;

constexpr int nB = 2;
constexpr int nS = 2048;
constexpr int nHID = 2048;
constexpr int nH = 16;
constexpr int nKV = 8;
constexpr int nD = 128;
constexpr int QS = 4096;  // fused qkv row stride (elems)
constexpr float kEps = 1e-6f;
constexpr float kScale = 0.08838834764831845f;  // 1/sqrt(128)

__device__ inline float b2f(unsigned short u) {
  return __uint_as_float(((unsigned)u) << 16);
}
__device__ inline float bf2f(bf16 v) { return __bfloat162float(v); }
__device__ inline short f2bs(float f) {
  bf16 h = __float2bfloat16(f);
  return *reinterpret_cast<short*>(&h);
}
__device__ inline unsigned pack2bf(float a, float b) {
  return ((unsigned)(unsigned short)f2bs(b) << 16) |
         (unsigned)(unsigned short)f2bs(a);
}

__device__ inline void gload_lds16(const bf16* g, bf16* l) {
  __builtin_amdgcn_global_load_lds(
      (const __attribute__((address_space(1))) void*)g,
      (__attribute__((address_space(3))) void*)l, 16, 0, 0);
}

// ---------------------------------------------------------------------------
// fp32 -> bf16 elementwise convert (n multiple of 4)
// ---------------------------------------------------------------------------
__global__ __launch_bounds__(256) void cvt_f32_bf16(
    const float* __restrict__ src, bf16* __restrict__ dst, int n) {
  const int i = (blockIdx.x * 256 + threadIdx.x) * 4;
  if (i >= n) return;
  const float4 v = *reinterpret_cast<const float4*>(src + i);
  ushort4 o;
  o.x = (unsigned short)f2bs(v.x);
  o.y = (unsigned short)f2bs(v.y);
  o.z = (unsigned short)f2bs(v.z);
  o.w = (unsigned short)f2bs(v.w);
  *reinterpret_cast<ushort4*>(dst + i) = o;
}

// ---------------------------------------------------------------------------
// Transpose + convert: src[K][N] fp32 -> dst[N][Kd] bf16 (Kd = dst stride).
// ---------------------------------------------------------------------------
__global__ __launch_bounds__(256) void transpose_f32_bf16(
    const float* __restrict__ src, bf16* __restrict__ dst, int K, int N) {
  __shared__ float t[32][33];
  const int k0 = blockIdx.y * 32, n0 = blockIdx.x * 32;
  const int c = threadIdx.x & 31, r8 = threadIdx.x >> 5;
#pragma unroll
  for (int i = 0; i < 4; ++i)
    t[r8 + i * 8][c] = src[(size_t)(k0 + r8 + i * 8) * N + n0 + c];
  __syncthreads();
#pragma unroll
  for (int i = 0; i < 4; ++i)
    dst[(size_t)(n0 + r8 + i * 8) * K + k0 + c] =
        __float2bfloat16(t[c][r8 + i * 8]);
}

// ---------------------------------------------------------------------------
// 256x256 bf16 MFMA GEMM, counted-vmcnt double-buffer (T3/T4 + T5):
//   C[M][N] = A[M][K] @ Bt[N][K]^T, 512 threads = 8 waves (2m x 4n),
//   BK=64, LDS = 2 bufs x (A 256x64 + B 256x64) = 128 KiB.
//   Key property: vmcnt(8) at tile top (8 prefetch loads of tile t+1 stay in
//   flight across both barriers) — never vmcnt(0) in the main loop.
//   LDS swizzle pair (rule #21): source chunk ^= row&7, read chunk ^= row&7.
// ---------------------------------------------------------------------------
template <typename OUT_T>
__global__ __launch_bounds__(512) void gemm_8ph(
    const bf16* __restrict__ A, const bf16* __restrict__ Bt,
    OUT_T* __restrict__ C, int M, int N, int K) {
  __shared__ bf16 lds[2][2][256 * 64];
  const int tid = threadIdx.x;
  const int wave = tid >> 6, lane = tid & 63;
  const int lr = lane & 15, lg = lane >> 4;
  const int wm = wave >> 2, wn = wave & 3;
  const int m0 = blockIdx.y * 256, n0 = blockIdx.x * 256;

  const int srow = lane >> 3;          // row-in-8 per gload
  const int sch = (lane & 7) ^ srow;   // pre-swizzled source chunk
  const bf16* aSrc = A + (size_t)(m0 + wave * 8 + srow) * K + sch * 8;
  const bf16* bSrc = Bt + (size_t)(n0 + wave * 8 + srow) * K + sch * 8;

  f32x4 acc[8][4];
#pragma unroll
  for (int m = 0; m < 8; ++m)
#pragma unroll
    for (int n = 0; n < 4; ++n) acc[m][n] = (f32x4){0.f, 0.f, 0.f, 0.f};

  auto stage = [&](int kt, int buf) {
    bf16* al = &lds[buf][0][(wave * 8) * 64];
    bf16* bl = &lds[buf][1][(wave * 8) * 64];
#pragma unroll
    for (int j = 0; j < 4; ++j) {
      gload_lds16(aSrc + (size_t)(j * 64) * K + kt, al + j * 64 * 64);
      gload_lds16(bSrc + (size_t)(j * 64) * K + kt, bl + j * 64 * 64);
    }
  };

  auto compute = [&](int buf) {
    const bf16* Ab = &lds[buf][0][0];
    const bf16* Bb = &lds[buf][1][0];
#pragma unroll
    for (int kk = 0; kk < 2; ++kk) {
      short8v bfr[4];
#pragma unroll
      for (int n = 0; n < 4; ++n) {
        const int row = wn * 64 + n * 16 + lr;
        const int c = (kk * 4 + lg) ^ (row & 7);
        bfr[n] = *reinterpret_cast<const short8v*>(&Bb[row * 64 + c * 8]);
      }
#pragma unroll
      for (int mh = 0; mh < 2; ++mh) {
        short8v af[4];
#pragma unroll
        for (int mi = 0; mi < 4; ++mi) {
          const int row = wm * 128 + (mh * 4 + mi) * 16 + lr;
          const int c = (kk * 4 + lg) ^ (row & 7);
          af[mi] = *reinterpret_cast<const short8v*>(&Ab[row * 64 + c * 8]);
        }
        __builtin_amdgcn_s_setprio(1);
#pragma unroll
        for (int mi = 0; mi < 4; ++mi)
#pragma unroll
          for (int n = 0; n < 4; ++n)
            acc[mh * 4 + mi][n] = __builtin_amdgcn_mfma_f32_16x16x32_bf16(
                af[mi], bfr[n], acc[mh * 4 + mi][n], 0, 0, 0);
        __builtin_amdgcn_s_setprio(0);
      }
    }
  };

  const int NT = K / 64;
  stage(0, 0);
  stage(64, 1);
  for (int t = 0; t < NT - 1; ++t) {
    asm volatile("s_waitcnt vmcnt(8)" ::: "memory");  // tile t landed; t+1 in flight
    __builtin_amdgcn_s_barrier();
    __builtin_amdgcn_sched_barrier(0);
    compute(t & 1);
    __builtin_amdgcn_s_barrier();  // all waves done reading buf t&1
    if (t + 2 < NT) stage((t + 2) * 64, t & 1);
  }
  asm volatile("s_waitcnt vmcnt(0)" ::: "memory");
  __builtin_amdgcn_s_barrier();
  __builtin_amdgcn_sched_barrier(0);
  compute((NT - 1) & 1);

#pragma unroll
  for (int m = 0; m < 8; ++m)
#pragma unroll
    for (int n = 0; n < 4; ++n)
#pragma unroll
      for (int r = 0; r < 4; ++r) {
        const int row = m0 + wm * 128 + m * 16 + 4 * lg + r;
        const int col = n0 + wn * 64 + n * 16 + lr;
        if constexpr (sizeof(OUT_T) == 2)
          C[(size_t)row * N + col] = __float2bfloat16(acc[m][n][r]);
        else
          C[(size_t)row * N + col] = acc[m][n][r];
      }
}

// ---------------------------------------------------------------------------
// Per-head RMSNorm + RoPE, in place on bf16, strided rows (fused qkv buffer).
// ---------------------------------------------------------------------------
__global__ __launch_bounds__(128) void norm_rope_kernel(
    bf16* __restrict__ x, const float* __restrict__ w, int rowStride) {
  const int row = blockIdx.x;
  const int head = blockIdx.y;
  const int t = threadIdx.x;
  const int s = row & (nS - 1);
  bf16* xp = x + (size_t)row * rowStride + head * nD;
  const float v = bf2f(xp[t]);
  float ss = v * v;
#pragma unroll
  for (int off = 32; off > 0; off >>= 1) ss += __shfl_xor(ss, off);
  __shared__ float wsum[2];
  __shared__ float buf[nD];
  if ((t & 63) == 0) wsum[t >> 6] = ss;
  __syncthreads();
  const float inv = rsqrtf((wsum[0] + wsum[1]) * (1.0f / nD) + kEps);
  const float nv = v * inv * w[t];
  buf[t] = nv;
  __syncthreads();
  const float partner = buf[t ^ 64];
  const float rot = (t < 64) ? -partner : partner;
  const int j = t & 63;
  const float invf = expf(-(float)j * (13.815510557964274f / 64.0f));
  const float ang = (float)s * invf;
  const float outv = nv * cosf(ang) + rot * sinf(ang);
  xp[t] = __float2bfloat16(outv);
}

// ---------------------------------------------------------------------------
// MFMA causal GQA flash attention (round-5 verified structure), reading the
// fused qkv buffer: Q at col h*128, K at 2048+kvh*128, V at 3072+kvh*128,
// row stride QS=4096.
// ---------------------------------------------------------------------------
constexpr int BQ = 64, BKT = 64;

__global__ __launch_bounds__(256) void attn_mfma(
    const bf16* __restrict__ QKV, bf16* __restrict__ O) {
  const int pair = blockIdx.x;  // 0..15
  const int bh = blockIdx.y;
  const int b = bh >> 4, h = bh & 15, kvh = h >> 1;
  const int tid = threadIdx.x;
  const int wave = tid >> 6, lane = tid & 63;
  const int lr = lane & 15, lg = lane >> 4;

  __shared__ bf16 Ks[BKT][136];
  __shared__ bf16 Vt[nD][72];
  __shared__ bf16 Pl[4][16][72];

  const bf16* Qbase = QKV + (size_t)b * nS * QS + h * nD;
  const bf16* Kbase = QKV + (size_t)b * nS * QS + 2048 + kvh * nD;
  const bf16* Vbase = QKV + (size_t)b * nS * QS + 3072 + kvh * nD;

  const int krow = tid >> 2, kcc = (tid & 3) * 32;
  const int vkey = tid & 63, vdc = (tid >> 6) * 32;

  short8v kreg[4], vreg[4];
  auto gload = [&](int kt) {
    const bf16* ksrc = Kbase + (size_t)(kt + krow) * QS + kcc;
    const bf16* vsrc = Vbase + (size_t)(kt + vkey) * QS + vdc;
#pragma unroll
    for (int i = 0; i < 4; ++i) {
      kreg[i] = *reinterpret_cast<const short8v*>(ksrc + 8 * i);
      vreg[i] = *reinterpret_cast<const short8v*>(vsrc + 8 * i);
    }
  };
  auto lwrite = [&]() {
#pragma unroll
    for (int i = 0; i < 4; ++i)
      *reinterpret_cast<short8v*>(&Ks[krow][kcc + 8 * i]) = kreg[i];
#pragma unroll
    for (int i = 0; i < 4; ++i)
#pragma unroll
      for (int j = 0; j < 8; ++j)
        *reinterpret_cast<short*>(&Vt[vdc + 8 * i + j][vkey]) = vreg[i][j];
  };

  short8v qf[4];
  f32x4 of[8];
  float m_run, l_run;

  auto load_q = [&](int q0) {
    const bf16* qrow = Qbase + (size_t)(q0 + 16 * wave + lr) * QS;
#pragma unroll
    for (int dc = 0; dc < 4; ++dc)
      qf[dc] = *reinterpret_cast<const short8v*>(qrow + 32 * dc + 8 * lg);
  };

  auto run_tiles = [&](int q0, int nt, bool stage_next0) {
    m_run = -1e30f;
    l_run = 0.f;
#pragma unroll
    for (int n = 0; n < 8; ++n) of[n] = (f32x4){0.f, 0.f, 0.f, 0.f};
    for (int j = 0; j < nt; ++j) {
      const int kt = j * BKT;
      const bool have_next = (j + 1 < nt) || stage_next0;
      const int ktn = (j + 1 < nt) ? (j + 1) * BKT : 0;
      if (have_next) gload(ktn);  // T14: issue early, write after barrier

      f32x4 s[4];
      __builtin_amdgcn_s_setprio(1);
#pragma unroll
      for (int sub = 0; sub < 4; ++sub) {
        f32x4 acc = {0.f, 0.f, 0.f, 0.f};
#pragma unroll
        for (int dc = 0; dc < 4; ++dc) {
          const short8v kf = *reinterpret_cast<const short8v*>(
              &Ks[16 * sub + lr][32 * dc + 8 * lg]);
          acc = __builtin_amdgcn_mfma_f32_16x16x32_bf16(kf, qf[dc], acc, 0, 0,
                                                        0);
        }
        s[sub] = acc;
      }
      __builtin_amdgcn_s_setprio(0);

      const bool diag = (kt == q0);
#pragma unroll
      for (int sub = 0; sub < 4; ++sub)
#pragma unroll
        for (int r = 0; r < 4; ++r) {
          float v = s[sub][r] * kScale;
          if (diag && (16 * sub + 4 * lg + r > 16 * wave + lr)) v = -1e30f;
          s[sub][r] = v;
        }

      float pmax = -1e30f;
#pragma unroll
      for (int sub = 0; sub < 4; ++sub)
#pragma unroll
        for (int r = 0; r < 4; ++r) pmax = fmaxf(pmax, s[sub][r]);
      pmax = fmaxf(pmax, __shfl_xor(pmax, 16));
      pmax = fmaxf(pmax, __shfl_xor(pmax, 32));

      if (!__all(pmax - m_run <= 8.f)) {  // T13 defer-rescale
        const float mt = fmaxf(m_run, pmax);
        const float corr = __expf(m_run - mt);
#pragma unroll
        for (int n = 0; n < 8; ++n) of[n] *= corr;
        l_run *= corr;
        m_run = mt;
      }

      float p[4][4];
      float lsum = 0.f;
#pragma unroll
      for (int sub = 0; sub < 4; ++sub)
#pragma unroll
        for (int r = 0; r < 4; ++r) {
          const float e = __expf(s[sub][r] - m_run);
          p[sub][r] = e;
          lsum += e;
        }
      lsum += __shfl_xor(lsum, 16);
      lsum += __shfl_xor(lsum, 32);
      l_run += lsum;

#pragma unroll
      for (int sub = 0; sub < 4; ++sub)
#pragma unroll
        for (int rp = 0; rp < 2; ++rp)
          *reinterpret_cast<unsigned*>(
              &Pl[wave][lr][16 * sub + 4 * lg + 2 * rp]) =
              pack2bf(p[sub][2 * rp], p[sub][2 * rp + 1]);

      __builtin_amdgcn_s_setprio(1);
#pragma unroll
      for (int kk = 0; kk < 2; ++kk) {
        const short8v pb = *reinterpret_cast<const short8v*>(
            &Pl[wave][lr][32 * kk + 8 * lg]);
#pragma unroll
        for (int n = 0; n < 8; ++n) {
          const short8v vf = *reinterpret_cast<const short8v*>(
              &Vt[16 * n + lr][32 * kk + 8 * lg]);
          of[n] =
              __builtin_amdgcn_mfma_f32_16x16x32_bf16(vf, pb, of[n], 0, 0, 0);
        }
      }
      __builtin_amdgcn_s_setprio(0);

      if (have_next) {
        __syncthreads();
        lwrite();
        __syncthreads();
      }
    }
  };

  auto epilogue = [&](int q0) {
    const float inv = 1.0f / l_run;
    bf16* orow =
        O + ((size_t)(b * nS + q0 + 16 * wave + lr)) * (nH * nD) + h * nD +
        4 * lg;
#pragma unroll
    for (int n = 0; n < 8; ++n)
#pragma unroll
      for (int rp = 0; rp < 2; ++rp)
        *reinterpret_cast<unsigned*>(orow + 16 * n + 2 * rp) =
            pack2bf(of[n][2 * rp] * inv, of[n][2 * rp + 1] * inv);
  };

  const int qh = (31 - pair) * BQ, nth = 32 - pair;
  const int ql = pair * BQ, ntl = pair + 1;

  gload(0);
  lwrite();
  __syncthreads();

  load_q(qh);
  run_tiles(qh, nth, true);
  epilogue(qh);

  load_q(ql);
  run_tiles(ql, ntl, false);
  epilogue(ql);
}

// ---------------------------------------------------------------------------
extern "C" void kernel_launch(void* const* d_in, const int* in_sizes, int n_in,
                              void* d_out, int out_size, void* d_ws,
                              size_t ws_size, hipStream_t stream) {
  const float* hs = (const float*)d_in[0];
  const float* Wq = (const float*)d_in[1];
  const float* Wk = (const float*)d_in[2];
  const float* Wv = (const float*)d_in[3];
  const float* Wo = (const float*)d_in[4];
  const float* qw = (const float*)d_in[5];
  const float* kw = (const float*)d_in[6];

  const int M = nB * nS;  // 4096
  char* ws = (char*)d_ws;
  size_t off = 0;
  auto alloc = [&](size_t bytes) {
    char* p = ws + off;
    off += bytes;
    return p;
  };
  bf16* hsb = (bf16*)alloc((size_t)M * nHID * 2);   // 16.8 MB
  bf16* att = hsb;                                  // reused after QKV GEMM
  bf16* qkv = (bf16*)alloc((size_t)M * QS * 2);     // 33.6 MB
  bf16* Wcat = (bf16*)alloc((size_t)QS * nHID * 2); // 16.8 MB
  bf16* Wot = (bf16*)alloc((size_t)nH * nD * nHID * 2);
  float* out = (float*)d_out;

  const int nHsElems = M * nHID;
  cvt_f32_bf16<<<(nHsElems / 4 + 255) / 256, 256, 0, stream>>>(hs, hsb,
                                                               nHsElems);
  // Wcat rows: [0,2048)=Wq^T, [2048,3072)=Wk^T, [3072,4096)=Wv^T
  transpose_f32_bf16<<<dim3(nH * nD / 32, nHID / 32), 256, 0, stream>>>(
      Wq, Wcat, nHID, nH * nD);
  transpose_f32_bf16<<<dim3(nKV * nD / 32, nHID / 32), 256, 0, stream>>>(
      Wk, Wcat + (size_t)2048 * nHID, nHID, nKV * nD);
  transpose_f32_bf16<<<dim3(nKV * nD / 32, nHID / 32), 256, 0, stream>>>(
      Wv, Wcat + (size_t)3072 * nHID, nHID, nKV * nD);
  transpose_f32_bf16<<<dim3(nHID / 32, nH * nD / 32), 256, 0, stream>>>(
      Wo, Wot, nH * nD, nHID);

  // fused QKV projection: [4096 x 2048] @ [2048 x 4096] -> qkv
  gemm_8ph<bf16><<<dim3(QS / 256, M / 256), 512, 0, stream>>>(
      hsb, Wcat, qkv, M, QS, nHID);

  norm_rope_kernel<<<dim3(M, nH), 128, 0, stream>>>(qkv, qw, QS);
  norm_rope_kernel<<<dim3(M, nKV), 128, 0, stream>>>(qkv + 2048, kw, QS);

  attn_mfma<<<dim3(16, nB * nH), 256, 0, stream>>>(qkv, att);

  gemm_8ph<float><<<dim3(nHID / 256, M / 256), 512, 0, stream>>>(
      att, Wot, out, M, nHID, nH * nD);
}

// Round 7
// 262.036 us; speedup vs baseline: 38.9244x; 1.0898x over previous
//
#include <hip/hip_runtime.h>
#include <hip/hip_bf16.h>

typedef __hip_bfloat16 bf16;
typedef __attribute__((ext_vector_type(8))) short short8v;
typedef __attribute__((ext_vector_type(4))) float f32x4;

constexpr int nB = 2;
constexpr int nS = 2048;
constexpr int nHID = 2048;
constexpr int nH = 16;
constexpr int nKV = 8;
constexpr int nD = 128;
constexpr int QS = 4096;  // fused qkv row stride (elems)
constexpr float kEps = 1e-6f;
constexpr float kScale = 0.08838834764831845f;  // 1/sqrt(128)

template <int N>
struct IC {
  static constexpr int value = N;
};

__device__ inline float b2f(unsigned short u) {
  return __uint_as_float(((unsigned)u) << 16);
}
__device__ inline float bf2f(bf16 v) { return __bfloat162float(v); }
__device__ inline short f2bs(float f) {
  bf16 h = __float2bfloat16(f);
  return *reinterpret_cast<short*>(&h);
}
__device__ inline unsigned pack2bf(float a, float b) {
  return ((unsigned)(unsigned short)f2bs(b) << 16) |
         (unsigned)(unsigned short)f2bs(a);
}

__device__ inline void gload_lds16(const bf16* g, bf16* l) {
  __builtin_amdgcn_global_load_lds(
      (const __attribute__((address_space(1))) void*)g,
      (__attribute__((address_space(3))) void*)l, 16, 0, 0);
}

template <int N>
__device__ inline void vwait() {
  asm volatile("s_waitcnt vmcnt(%0)" ::"n"(N) : "memory");
}

// ---------------------------------------------------------------------------
// fp32 -> bf16 elementwise convert (n multiple of 4)
// ---------------------------------------------------------------------------
__global__ __launch_bounds__(256) void cvt_f32_bf16(
    const float* __restrict__ src, bf16* __restrict__ dst, int n) {
  const int i = (blockIdx.x * 256 + threadIdx.x) * 4;
  if (i >= n) return;
  const float4 v = *reinterpret_cast<const float4*>(src + i);
  ushort4 o;
  o.x = (unsigned short)f2bs(v.x);
  o.y = (unsigned short)f2bs(v.y);
  o.z = (unsigned short)f2bs(v.z);
  o.w = (unsigned short)f2bs(v.w);
  *reinterpret_cast<ushort4*>(dst + i) = o;
}

// ---------------------------------------------------------------------------
// Transpose + convert: src[K][N] fp32 -> dst[N][K] bf16. 32x32 tiles.
// ---------------------------------------------------------------------------
__global__ __launch_bounds__(256) void transpose_f32_bf16(
    const float* __restrict__ src, bf16* __restrict__ dst, int K, int N) {
  __shared__ float t[32][33];
  const int k0 = blockIdx.y * 32, n0 = blockIdx.x * 32;
  const int c = threadIdx.x & 31, r8 = threadIdx.x >> 5;
#pragma unroll
  for (int i = 0; i < 4; ++i)
    t[r8 + i * 8][c] = src[(size_t)(k0 + r8 + i * 8) * N + n0 + c];
  __syncthreads();
#pragma unroll
  for (int i = 0; i < 4; ++i)
    dst[(size_t)(n0 + r8 + i * 8) * K + k0 + c] =
        __float2bfloat16(t[c][r8 + i * 8]);
}

// ---------------------------------------------------------------------------
// Per-phase-interleaved 8-phase MFMA GEMM (T2-equivalent layout + T3/T4/T5):
//   C[M][N] = A[M][K] @ Bt[N][K]^T.  BN=256 fixed, BM in {256,128}.
//   512 threads = 8 waves (2m x 4n); wave owns BM/2 x 64.
//   LDS: [2 buf][A k-half0, A k-half1, B k-half0, B k-half1], each khalf
//   [rows][32] bf16 (64B rows -> conflict-free b128 frag reads, no swizzle).
//   Per K-tile: 4 phases (kk,mh); each phase stages ONE half-tile (A:LA or
//   B:2 gloads) and computes one fragment quadrant. Steady-state
//   vmcnt(2LA+2LB) at phases 1,3 — never 0 in the main loop.
//   Stage order: p1:A-k1(t+1) p2:B-k1(t+1) p3:A-k0(t+2) p4:B-k0(t+2).
//   Safety: k0(t) reads drain by each wave's p2 lgkmcnt(0); p3's barrier
//   orders that before the k0(t+2) overwrite (same buf). k1 regions are only
//   overwritten from the opposite buf's tile. Last tile peeled: waits LA+LB, 0.
// ---------------------------------------------------------------------------
template <int BM, typename OUT_T>
__global__ __launch_bounds__(512) void gemm_8ph(
    const bf16* __restrict__ A, const bf16* __restrict__ Bt,
    OUT_T* __restrict__ C, int M, int N, int K) {
  constexpr int LA = BM / 128;      // gloads per A k-half
  constexpr int LB = 2;             // gloads per B k-half
  constexpr int MF = BM / 32;       // A frags per wave
  constexpr int MFH = MF / 2;       // A frags per phase
  constexpr int W = 2 * (LA + LB);  // steady-state vmcnt
  constexpr int LDSB = 2 * BM * 32 + 2 * 256 * 32;  // elems per buffer
  __shared__ bf16 lds[2 * LDSB];

  const int tid = threadIdx.x;
  const int wave = tid >> 6, lane = tid & 63;
  const int lr = lane & 15, lg = lane >> 4;
  const int wm = wave >> 2, wn = wave & 3;
  const int m0 = blockIdx.y * BM, n0 = blockIdx.x * 256;
  const int srow = tid >> 2, scol = (tid & 3) * 8;

  auto stageA = [&](int t, int kk) {
    bf16* dst = lds + (t & 1) * LDSB + kk * (BM * 32) + wave * 512;
    const bf16* src = A + (size_t)(m0 + srow) * K + t * 64 + kk * 32 + scol;
#pragma unroll
    for (int j = 0; j < LA; ++j)
      gload_lds16(src + (size_t)(j * 128) * K, dst + j * 4096);
  };
  auto stageB = [&](int t, int kk) {
    bf16* dst =
        lds + (t & 1) * LDSB + 2 * BM * 32 + kk * (256 * 32) + wave * 512;
    const bf16* src = Bt + (size_t)(n0 + srow) * K + t * 64 + kk * 32 + scol;
#pragma unroll
    for (int j = 0; j < LB; ++j)
      gload_lds16(src + (size_t)(j * 128) * K, dst + j * 4096);
  };

  f32x4 acc[MF][4];
#pragma unroll
  for (int m = 0; m < MF; ++m)
#pragma unroll
    for (int n = 0; n < 4; ++n) acc[m][n] = (f32x4){0.f, 0.f, 0.f, 0.f};
  short8v bfr[4];

  auto phase = [&](auto WC, int buf, int kk, int mh, auto stageFn) {
    constexpr int WAIT = decltype(WC)::value;
    if constexpr (WAIT >= 0) vwait<WAIT>();
    __builtin_amdgcn_s_barrier();
    asm volatile("" ::: "memory");
    if (mh == 0) {  // B frags for this kk (reused by mh=1 phase)
      const bf16* bb = lds + buf * LDSB + 2 * BM * 32 + kk * (256 * 32);
#pragma unroll
      for (int ni = 0; ni < 4; ++ni)
        bfr[ni] = *reinterpret_cast<const short8v*>(
            bb + (wn * 64 + ni * 16 + lr) * 32 + lg * 8);
    }
    short8v af[MFH];
    const bf16* ab = lds + buf * LDSB + kk * (BM * 32);
#pragma unroll
    for (int ii = 0; ii < MFH; ++ii)
      af[ii] = *reinterpret_cast<const short8v*>(
          ab + (wm * (BM / 2) + (mh * MFH + ii) * 16 + lr) * 32 + lg * 8);
    stageFn();
    asm volatile("s_waitcnt lgkmcnt(0)" ::: "memory");
    __builtin_amdgcn_sched_barrier(0);
    __builtin_amdgcn_s_setprio(1);
#pragma unroll
    for (int ii = 0; ii < MFH; ++ii)
#pragma unroll
      for (int ni = 0; ni < 4; ++ni)
        acc[mh * MFH + ii][ni] = __builtin_amdgcn_mfma_f32_16x16x32_bf16(
            af[ii], bfr[ni], acc[mh * MFH + ii][ni], 0, 0, 0);
    __builtin_amdgcn_s_setprio(0);
  };

  const int NT = K / 64;
  // prologue: k0(0), k1(0), k0(1)  (issue order matters for vmcnt counts)
  stageA(0, 0);
  stageB(0, 0);
  stageA(0, 1);
  stageB(0, 1);
  stageA(1, 0);
  stageB(1, 0);

  for (int t = 0; t < NT - 1; ++t) {
    const int buf = t & 1;
    phase(IC<W>{}, buf, 0, 0, [&] { stageA(t + 1, 1); });
    phase(IC<-1>{}, buf, 0, 1, [&] { stageB(t + 1, 1); });
    phase(IC<W>{}, buf, 1, 0, [&] {
      if (t < NT - 2) stageA(t + 2, 0);
    });
    phase(IC<-1>{}, buf, 1, 1, [&] {
      if (t < NT - 2) stageB(t + 2, 0);
    });
  }
  {  // peeled last tile: no staging; drain waits LA+LB then 0
    const int buf = (NT - 1) & 1;
    phase(IC<LA + LB>{}, buf, 0, 0, [&] {});
    phase(IC<-1>{}, buf, 0, 1, [&] {});
    phase(IC<0>{}, buf, 1, 0, [&] {});
    phase(IC<-1>{}, buf, 1, 1, [&] {});
  }

#pragma unroll
  for (int m = 0; m < MF; ++m)
#pragma unroll
    for (int n = 0; n < 4; ++n)
#pragma unroll
      for (int r = 0; r < 4; ++r) {
        const int row = m0 + wm * (BM / 2) + m * 16 + 4 * lg + r;
        const int col = n0 + wn * 64 + n * 16 + lr;
        if constexpr (sizeof(OUT_T) == 2)
          C[(size_t)row * N + col] = __float2bfloat16(acc[m][n][r]);
        else
          C[(size_t)row * N + col] = acc[m][n][r];
      }
}

// ---------------------------------------------------------------------------
// Per-head RMSNorm + RoPE on the fused qkv buffer, q and k in one launch.
// Grid: (M, 24): head 0..15 -> q cols h*128; 16..23 -> k cols 2048+(h-16)*128.
// ---------------------------------------------------------------------------
__global__ __launch_bounds__(128) void norm_rope_fused(
    bf16* __restrict__ qkv, const float* __restrict__ qw,
    const float* __restrict__ kw) {
  const int row = blockIdx.x;
  const int head = blockIdx.y;
  const int t = threadIdx.x;
  const int s = row & (nS - 1);
  const bool isQ = head < nH;
  const int col = isQ ? head * nD : 2048 + (head - nH) * nD;
  const float* w = isQ ? qw : kw;
  bf16* xp = qkv + (size_t)row * QS + col;
  const float v = bf2f(xp[t]);
  float ss = v * v;
#pragma unroll
  for (int off = 32; off > 0; off >>= 1) ss += __shfl_xor(ss, off);
  __shared__ float wsum[2];
  __shared__ float buf[nD];
  if ((t & 63) == 0) wsum[t >> 6] = ss;
  __syncthreads();
  const float inv = rsqrtf((wsum[0] + wsum[1]) * (1.0f / nD) + kEps);
  const float nv = v * inv * w[t];
  buf[t] = nv;
  __syncthreads();
  const float partner = buf[t ^ 64];
  const float rot = (t < 64) ? -partner : partner;
  const int j = t & 63;
  const float invf = expf(-(float)j * (13.815510557964274f / 64.0f));
  const float ang = (float)s * invf;
  const float outv = nv * cosf(ang) + rot * sinf(ang);
  xp[t] = __float2bfloat16(outv);
}

// ---------------------------------------------------------------------------
// MFMA causal GQA flash attention (round-5 verified structure), reading the
// fused qkv buffer: Q at col h*128, K at 2048+kvh*128, V at 3072+kvh*128.
// ---------------------------------------------------------------------------
constexpr int BQ = 64, BKT = 64;

__global__ __launch_bounds__(256) void attn_mfma(
    const bf16* __restrict__ QKV, bf16* __restrict__ O) {
  const int pair = blockIdx.x;  // 0..15
  const int bh = blockIdx.y;
  const int b = bh >> 4, h = bh & 15, kvh = h >> 1;
  const int tid = threadIdx.x;
  const int wave = tid >> 6, lane = tid & 63;
  const int lr = lane & 15, lg = lane >> 4;

  __shared__ bf16 Ks[BKT][136];
  __shared__ bf16 Vt[nD][72];
  __shared__ bf16 Pl[4][16][72];

  const bf16* Qbase = QKV + (size_t)b * nS * QS + h * nD;
  const bf16* Kbase = QKV + (size_t)b * nS * QS + 2048 + kvh * nD;
  const bf16* Vbase = QKV + (size_t)b * nS * QS + 3072 + kvh * nD;

  const int krow = tid >> 2, kcc = (tid & 3) * 32;
  const int vkey = tid & 63, vdc = (tid >> 6) * 32;

  short8v kreg[4], vreg[4];
  auto gload = [&](int kt) {
    const bf16* ksrc = Kbase + (size_t)(kt + krow) * QS + kcc;
    const bf16* vsrc = Vbase + (size_t)(kt + vkey) * QS + vdc;
#pragma unroll
    for (int i = 0; i < 4; ++i) {
      kreg[i] = *reinterpret_cast<const short8v*>(ksrc + 8 * i);
      vreg[i] = *reinterpret_cast<const short8v*>(vsrc + 8 * i);
    }
  };
  auto lwrite = [&]() {
#pragma unroll
    for (int i = 0; i < 4; ++i)
      *reinterpret_cast<short8v*>(&Ks[krow][kcc + 8 * i]) = kreg[i];
#pragma unroll
    for (int i = 0; i < 4; ++i)
#pragma unroll
      for (int j = 0; j < 8; ++j)
        *reinterpret_cast<short*>(&Vt[vdc + 8 * i + j][vkey]) = vreg[i][j];
  };

  short8v qf[4];
  f32x4 of[8];
  float m_run, l_run;

  auto load_q = [&](int q0) {
    const bf16* qrow = Qbase + (size_t)(q0 + 16 * wave + lr) * QS;
#pragma unroll
    for (int dc = 0; dc < 4; ++dc)
      qf[dc] = *reinterpret_cast<const short8v*>(qrow + 32 * dc + 8 * lg);
  };

  auto run_tiles = [&](int q0, int nt, bool stage_next0) {
    m_run = -1e30f;
    l_run = 0.f;
#pragma unroll
    for (int n = 0; n < 8; ++n) of[n] = (f32x4){0.f, 0.f, 0.f, 0.f};
    for (int j = 0; j < nt; ++j) {
      const int kt = j * BKT;
      const bool have_next = (j + 1 < nt) || stage_next0;
      const int ktn = (j + 1 < nt) ? (j + 1) * BKT : 0;
      if (have_next) gload(ktn);  // T14: issue early, write after barrier

      f32x4 s[4];
      __builtin_amdgcn_s_setprio(1);
#pragma unroll
      for (int sub = 0; sub < 4; ++sub) {
        f32x4 acc = {0.f, 0.f, 0.f, 0.f};
#pragma unroll
        for (int dc = 0; dc < 4; ++dc) {
          const short8v kf = *reinterpret_cast<const short8v*>(
              &Ks[16 * sub + lr][32 * dc + 8 * lg]);
          acc = __builtin_amdgcn_mfma_f32_16x16x32_bf16(kf, qf[dc], acc, 0, 0,
                                                        0);
        }
        s[sub] = acc;
      }
      __builtin_amdgcn_s_setprio(0);

      const bool diag = (kt == q0);
#pragma unroll
      for (int sub = 0; sub < 4; ++sub)
#pragma unroll
        for (int r = 0; r < 4; ++r) {
          float v = s[sub][r] * kScale;
          if (diag && (16 * sub + 4 * lg + r > 16 * wave + lr)) v = -1e30f;
          s[sub][r] = v;
        }

      float pmax = -1e30f;
#pragma unroll
      for (int sub = 0; sub < 4; ++sub)
#pragma unroll
        for (int r = 0; r < 4; ++r) pmax = fmaxf(pmax, s[sub][r]);
      pmax = fmaxf(pmax, __shfl_xor(pmax, 16));
      pmax = fmaxf(pmax, __shfl_xor(pmax, 32));

      if (!__all(pmax - m_run <= 8.f)) {  // T13 defer-rescale
        const float mt = fmaxf(m_run, pmax);
        const float corr = __expf(m_run - mt);
#pragma unroll
        for (int n = 0; n < 8; ++n) of[n] *= corr;
        l_run *= corr;
        m_run = mt;
      }

      float p[4][4];
      float lsum = 0.f;
#pragma unroll
      for (int sub = 0; sub < 4; ++sub)
#pragma unroll
        for (int r = 0; r < 4; ++r) {
          const float e = __expf(s[sub][r] - m_run);
          p[sub][r] = e;
          lsum += e;
        }
      lsum += __shfl_xor(lsum, 16);
      lsum += __shfl_xor(lsum, 32);
      l_run += lsum;

#pragma unroll
      for (int sub = 0; sub < 4; ++sub)
#pragma unroll
        for (int rp = 0; rp < 2; ++rp)
          *reinterpret_cast<unsigned*>(
              &Pl[wave][lr][16 * sub + 4 * lg + 2 * rp]) =
              pack2bf(p[sub][2 * rp], p[sub][2 * rp + 1]);

      __builtin_amdgcn_s_setprio(1);
#pragma unroll
      for (int kk = 0; kk < 2; ++kk) {
        const short8v pb = *reinterpret_cast<const short8v*>(
            &Pl[wave][lr][32 * kk + 8 * lg]);
#pragma unroll
        for (int n = 0; n < 8; ++n) {
          const short8v vf = *reinterpret_cast<const short8v*>(
              &Vt[16 * n + lr][32 * kk + 8 * lg]);
          of[n] =
              __builtin_amdgcn_mfma_f32_16x16x32_bf16(vf, pb, of[n], 0, 0, 0);
        }
      }
      __builtin_amdgcn_s_setprio(0);

      if (have_next) {
        __syncthreads();
        lwrite();
        __syncthreads();
      }
    }
  };

  auto epilogue = [&](int q0) {
    const float inv = 1.0f / l_run;
    bf16* orow = O + ((size_t)(b * nS + q0 + 16 * wave + lr)) * (nH * nD) +
                 h * nD + 4 * lg;
#pragma unroll
    for (int n = 0; n < 8; ++n)
#pragma unroll
      for (int rp = 0; rp < 2; ++rp)
        *reinterpret_cast<unsigned*>(orow + 16 * n + 2 * rp) =
            pack2bf(of[n][2 * rp] * inv, of[n][2 * rp + 1] * inv);
  };

  const int qh = (31 - pair) * BQ, nth = 32 - pair;
  const int ql = pair * BQ, ntl = pair + 1;

  gload(0);
  lwrite();
  __syncthreads();

  load_q(qh);
  run_tiles(qh, nth, true);
  epilogue(qh);

  load_q(ql);
  run_tiles(ql, ntl, false);
  epilogue(ql);
}

// ---------------------------------------------------------------------------
extern "C" void kernel_launch(void* const* d_in, const int* in_sizes, int n_in,
                              void* d_out, int out_size, void* d_ws,
                              size_t ws_size, hipStream_t stream) {
  const float* hs = (const float*)d_in[0];
  const float* Wq = (const float*)d_in[1];
  const float* Wk = (const float*)d_in[2];
  const float* Wv = (const float*)d_in[3];
  const float* Wo = (const float*)d_in[4];
  const float* qw = (const float*)d_in[5];
  const float* kw = (const float*)d_in[6];

  const int M = nB * nS;  // 4096
  char* ws = (char*)d_ws;
  size_t off = 0;
  auto alloc = [&](size_t bytes) {
    char* p = ws + off;
    off += bytes;
    return p;
  };
  bf16* hsb = (bf16*)alloc((size_t)M * nHID * 2);    // 16.8 MB
  bf16* att = hsb;                                   // reused after QKV GEMM
  bf16* qkv = (bf16*)alloc((size_t)M * QS * 2);      // 33.6 MB
  bf16* Wcat = (bf16*)alloc((size_t)QS * nHID * 2);  // 16.8 MB
  bf16* Wot = (bf16*)alloc((size_t)nH * nD * nHID * 2);
  float* out = (float*)d_out;

  const int nHsElems = M * nHID;
  cvt_f32_bf16<<<(nHsElems / 4 + 255) / 256, 256, 0, stream>>>(hs, hsb,
                                                               nHsElems);
  // Wcat rows: [0,2048)=Wq^T, [2048,3072)=Wk^T, [3072,4096)=Wv^T
  transpose_f32_bf16<<<dim3(nH * nD / 32, nHID / 32), 256, 0, stream>>>(
      Wq, Wcat, nHID, nH * nD);
  transpose_f32_bf16<<<dim3(nKV * nD / 32, nHID / 32), 256, 0, stream>>>(
      Wk, Wcat + (size_t)2048 * nHID, nHID, nKV * nD);
  transpose_f32_bf16<<<dim3(nKV * nD / 32, nHID / 32), 256, 0, stream>>>(
      Wv, Wcat + (size_t)3072 * nHID, nHID, nKV * nD);
  transpose_f32_bf16<<<dim3(nHID / 32, nH * nD / 32), 256, 0, stream>>>(
      Wo, Wot, nH * nD, nHID);

  // fused QKV projection: [4096 x 2048] @ [2048 x 4096]^T-layout -> qkv
  gemm_8ph<256, bf16><<<dim3(QS / 256, M / 256), 512, 0, stream>>>(
      hsb, Wcat, qkv, M, QS, nHID);

  norm_rope_fused<<<dim3(M, nH + nKV), 128, 0, stream>>>(qkv, qw, kw);

  attn_mfma<<<dim3(16, nB * nH), 256, 0, stream>>>(qkv, att);

  // output projection: [4096 x 2048] @ [2048 x 2048] -> out (fp32)
  gemm_8ph<128, float><<<dim3(nHID / 256, M / 128), 512, 0, stream>>>(
      att, Wot, out, M, nHID, nH * nD);
}